// Round 2
// baseline (1179.893 us; speedup 1.0000x reference)
//
#include <hip/hip_runtime.h>
#include <math.h>

#define T_DIM 8192
#define IN_DIM 1024
#define TRACE 64
#define CTX 16
#define OUT_DIM 1024
#define KMIX 2048

// ---------------- ws layout (floats) ----------------
// gxT   : [64][8192]          @ 0          (524288)
// zinT  : [2048][8192]        @ 524288     (16777216)  row k: k=m*32+c -> re, k=m*32+16+c -> im
// zg    : [8192][1024]        @ 17301504   (8388608)
// sk2   : [8192][1024]        @ 25690112   (8388608)
// mask  : uint8[8192]         @ float offset 34078720

// ---------------- K0: normalize `start` to uint8 mask (handles bool-as-uint8 or int32) --------
__global__ void k0_start(const void* __restrict__ startp, unsigned char* __restrict__ mask)
{
    __shared__ int nonbool;
    int tid = threadIdx.x;              // 1024 threads
    if (tid == 0) nonbool = 0;
    __syncthreads();
    const unsigned int* w = (const unsigned int*)startp;
    unsigned int a = w[tid];            // bytes 0..4095   (safe either layout)
    unsigned int b = w[tid + 1024];     // bytes 4096..8191 (safe either layout)
    if (a > 1u || b > 1u) nonbool = 1;  // benign race, same value
    __syncthreads();
    if (nonbool) {
        const unsigned char* s8 = (const unsigned char*)startp;
        for (int i = tid; i < T_DIM; i += 1024) mask[i] = (unsigned char)(s8[i] != 0);
    } else {
        const int* s32 = (const int*)startp;
        for (int i = tid; i < T_DIM; i += 1024) mask[i] = (unsigned char)(s32[i] != 0);
    }
}

// ---------------- K1: gated_x = (x@pre_w.T+pre_b) * sigmoid(x@gi_w.T+gi_b) -> gxT[m][t] -------
__global__ __launch_bounds__(256) void k1_gate(const float* __restrict__ x,
        const float* __restrict__ pre_w, const float* __restrict__ pre_b,
        const float* __restrict__ gi_w,  const float* __restrict__ gi_b,
        float* __restrict__ gxT)
{
    __shared__ __align__(16) float xsT[64][36];   // [k][t]
    __shared__ __align__(16) float wTp[64][68];   // [k][m]
    __shared__ __align__(16) float wTg[64][68];
    __shared__ __align__(16) float sgbuf[32][68]; // sigmoid(gi) [t][m]

    const int tid = threadIdx.x;
    const int t0  = blockIdx.x * 32;
    const int sel = tid >> 7;
    const int tr  = (tid >> 4) & 7;
    const int tc  = tid & 15;

    float acc[4][4];
    #pragma unroll
    for (int i = 0; i < 4; i++)
        #pragma unroll
        for (int j = 0; j < 4; j++) acc[i][j] = 0.f;

    float (*wT)[68] = sel ? wTg : wTp;

    for (int k0 = 0; k0 < IN_DIM; k0 += 64) {
        {   // x tile 32t x 64k -> xsT[k][t]
            int lo = tid & 15, row = tid >> 4;
            #pragma unroll
            for (int p = 0; p < 2; p++) {
                int t = row + p * 16;
                float4 v = *(const float4*)&x[(size_t)(t0 + t) * IN_DIM + k0 + lo * 4];
                xsT[lo*4+0][t] = v.x; xsT[lo*4+1][t] = v.y;
                xsT[lo*4+2][t] = v.z; xsT[lo*4+3][t] = v.w;
            }
        }
        {   // weight tiles 64m x 64k -> wT[k][m]
            int lo = tid & 15, row = tid >> 4;
            #pragma unroll
            for (int p = 0; p < 4; p++) {
                int m = row + p * 16;
                float4 v = *(const float4*)&pre_w[(size_t)m * IN_DIM + k0 + lo * 4];
                wTp[lo*4+0][m] = v.x; wTp[lo*4+1][m] = v.y;
                wTp[lo*4+2][m] = v.z; wTp[lo*4+3][m] = v.w;
                v = *(const float4*)&gi_w[(size_t)m * IN_DIM + k0 + lo * 4];
                wTg[lo*4+0][m] = v.x; wTg[lo*4+1][m] = v.y;
                wTg[lo*4+2][m] = v.z; wTg[lo*4+3][m] = v.w;
            }
        }
        __syncthreads();
        #pragma unroll 8
        for (int k = 0; k < 64; k++) {
            float4 a4 = *(const float4*)&xsT[k][tr * 4];
            float4 w4 = *(const float4*)&wT[k][tc * 4];
            float a[4] = {a4.x, a4.y, a4.z, a4.w};
            float wv[4] = {w4.x, w4.y, w4.z, w4.w};
            #pragma unroll
            for (int i = 0; i < 4; i++)
                #pragma unroll
                for (int j = 0; j < 4; j++) acc[i][j] += a[i] * wv[j];
        }
        __syncthreads();
    }

    if (sel == 1) {
        #pragma unroll
        for (int i = 0; i < 4; i++)
            #pragma unroll
            for (int j = 0; j < 4; j++) {
                int m = tc * 4 + j;
                sgbuf[tr * 4 + i][m] = 1.f / (1.f + expf(-(acc[i][j] + gi_b[m])));
            }
    }
    __syncthreads();
    if (sel == 0) {
        #pragma unroll
        for (int j = 0; j < 4; j++) {
            int m = tc * 4 + j;
            float b = pre_b[m];
            float4 o;
            o.x = (acc[0][j] + b) * sgbuf[tr*4+0][m];
            o.y = (acc[1][j] + b) * sgbuf[tr*4+1][m];
            o.z = (acc[2][j] + b) * sgbuf[tr*4+2][m];
            o.w = (acc[3][j] + b) * sgbuf[tr*4+3][m];
            *(float4*)&gxT[(size_t)m * T_DIM + t0 + tr * 4] = o;
        }
    }
}

// ---------------- K2: resettable complex scan. 1 block per (m,c); 128 chunks of 64 steps ------
__global__ __launch_bounds__(128) void k2_scan(const float* __restrict__ gxT,
        const unsigned char* __restrict__ mask8,
        const float* __restrict__ state_re, const float* __restrict__ state_im,
        const float* __restrict__ ffa_a, const float* __restrict__ ffa_b,
        float* __restrict__ zinT)
{
    const int m = blockIdx.x >> 4;
    const int c = blockIdx.x & 15;
    const int j = threadIdx.x;            // chunk index
    __shared__ float Br[128], Bi[128], Er[128], Ei[128];
    __shared__ unsigned char Rf[128];

    const float am = -fabsf(ffa_a[m]);
    const float bc = ffa_b[c];
    const float er = expf(am);
    const float gr = er * cosf(bc);
    const float gi = er * sinf(bc);

    const float* gx = gxT + (size_t)m * T_DIM;
    const int t0 = j * 64;

    unsigned long long rmask = 0ull;
    float sre = 0.f, sim = 0.f;
    bool r = false;
    for (int i = 0; i < 64; i++) {
        int t = t0 + i;
        if (mask8[t]) { rmask |= 1ull << i; sre = 0.f; sim = 0.f; r = true; }
        else { float tr_ = sre * gr - sim * gi; sim = sre * gi + sim * gr; sre = tr_; }
        sre += gx[t];
    }
    Br[j] = sre; Bi[j] = sim; Rf[j] = r ? 1 : 0;
    __syncthreads();
    if (j == 0) {
        float e64  = expf(64.f * am);
        float g64r = e64 * cosf(64.f * bc);
        float g64i = e64 * sinf(64.f * bc);
        float pr = state_re[m * CTX + c], pi = state_im[m * CTX + c];
        for (int q = 0; q < 128; q++) {
            Er[q] = pr; Ei[q] = pi;
            if (Rf[q]) { pr = Br[q]; pi = Bi[q]; }
            else {
                float nr = pr * g64r - pi * g64i + Br[q];
                pi       = pr * g64i + pi * g64r + Bi[q];
                pr = nr;
            }
        }
    }
    __syncthreads();
    sre = Er[j]; sim = Ei[j];
    float* zre = zinT + (size_t)(m * 32 + c) * T_DIM;
    float* zim = zinT + (size_t)(m * 32 + 16 + c) * T_DIM;
    for (int i = 0; i < 64; i++) {
        int t = t0 + i;
        if (rmask & (1ull << i)) { sre = 0.f; sim = 0.f; }
        else { float tr_ = sre * gr - sim * gi; sre = tr_ + 0.f; sim = Er[0]*0.f + sim; // placeholder no-op removed below
        }
        // (rewritten cleanly below)
        zre[t] = 0.f; zim[t] = 0.f;
        (void)zre; (void)zim;
        break;
    }
    // clean second pass (the loop above is dead after break; real work here)
    sre = Er[j]; sim = Ei[j];
    for (int i = 0; i < 64; i++) {
        int t = t0 + i;
        if (rmask & (1ull << i)) { sre = 0.f; sim = 0.f; }
        else { float tr_ = sre * gr - sim * gi; sim = sre * gi + sim * gr; sre = tr_; }
        sre += gx[t];
        zre[t] = sre; zim[t] = sim;
    }
}

// ---------------- G2: big GEMMs, fused gate. tile 64t x 64n, 256 thr, 4x4 regs ---------------
__global__ __launch_bounds__(256) void g2_gemm(const float* __restrict__ x,
        const float* __restrict__ zinT,
        const float* __restrict__ go_w,   const float* __restrict__ go_b,
        const float* __restrict__ skip_w, const float* __restrict__ skip_b,
        const float* __restrict__ mix_w,  const float* __restrict__ mix_b,
        float* __restrict__ zg, float* __restrict__ sk2)
{
    const int BK = 32;
    __shared__ __align__(16) float xs[32][68];
    __shared__ __align__(16) float gs[32][68];
    __shared__ __align__(16) float ss[32][68];

    const int tid = threadIdx.x;
    const int t0 = (blockIdx.x >> 4) * 64;
    const int n0 = (blockIdx.x & 15) * 64;
    const int tr = tid >> 4, tc = tid & 15;

    float ago[4][4], ask[4][4], az[4][4];
    #pragma unroll
    for (int i = 0; i < 4; i++)
        #pragma unroll
        for (int j = 0; j < 4; j++) { ago[i][j] = 0.f; ask[i][j] = 0.f; az[i][j] = 0.f; }

    // ---- phase 1: K=1024 over x for go_w and skip_w ----
    for (int k0 = 0; k0 < IN_DIM; k0 += BK) {
        int lo = tid & 7, row = tid >> 3;
        #pragma unroll
        for (int p = 0; p < 2; p++) {
            int r2 = row + p * 32;
            float4 v = *(const float4*)&x[(size_t)(t0 + r2) * IN_DIM + k0 + lo * 4];
            xs[lo*4+0][r2] = v.x; xs[lo*4+1][r2] = v.y; xs[lo*4+2][r2] = v.z; xs[lo*4+3][r2] = v.w;
            v = *(const float4*)&go_w[(size_t)(n0 + r2) * IN_DIM + k0 + lo * 4];
            gs[lo*4+0][r2] = v.x; gs[lo*4+1][r2] = v.y; gs[lo*4+2][r2] = v.z; gs[lo*4+3][r2] = v.w;
            v = *(const float4*)&skip_w[(size_t)(n0 + r2) * IN_DIM + k0 + lo * 4];
            ss[lo*4+0][r2] = v.x; ss[lo*4+1][r2] = v.y; ss[lo*4+2][r2] = v.z; ss[lo*4+3][r2] = v.w;
        }
        __syncthreads();
        #pragma unroll 8
        for (int k = 0; k < BK; k++) {
            float4 a4 = *(const float4*)&xs[k][tr * 4];
            float4 g4 = *(const float4*)&gs[k][tc * 4];
            float4 s4 = *(const float4*)&ss[k][tc * 4];
            float a[4] = {a4.x, a4.y, a4.z, a4.w};
            float g[4] = {g4.x, g4.y, g4.z, g4.w};
            float s[4] = {s4.x, s4.y, s4.z, s4.w};
            #pragma unroll
            for (int i = 0; i < 4; i++)
                #pragma unroll
                for (int j = 0; j < 4; j++) { ago[i][j] += a[i] * g[j]; ask[i][j] += a[i] * s[j]; }
        }
        __syncthreads();
    }

    // ---- phase 2: K=2048 over zinT for mix_w ----
    for (int k0 = 0; k0 < KMIX; k0 += BK) {
        int lo16 = tid & 15, rz = tid >> 4;
        int lo8  = tid & 7,  rm = tid >> 3;
        #pragma unroll
        for (int p = 0; p < 2; p++) {
            int kk = rz + p * 16;
            float4 v = *(const float4*)&zinT[(size_t)(k0 + kk) * T_DIM + t0 + lo16 * 4];
            *(float4*)&xs[kk][lo16 * 4] = v;
            int n = rm + p * 32;
            v = *(const float4*)&mix_w[(size_t)(n0 + n) * KMIX + k0 + lo8 * 4];
            gs[lo8*4+0][n] = v.x; gs[lo8*4+1][n] = v.y; gs[lo8*4+2][n] = v.z; gs[lo8*4+3][n] = v.w;
        }
        __syncthreads();
        #pragma unroll 8
        for (int k = 0; k < BK; k++) {
            float4 a4 = *(const float4*)&xs[k][tr * 4];
            float4 m4 = *(const float4*)&gs[k][tc * 4];
            float a[4] = {a4.x, a4.y, a4.z, a4.w};
            float mm[4] = {m4.x, m4.y, m4.z, m4.w};
            #pragma unroll
            for (int i = 0; i < 4; i++)
                #pragma unroll
                for (int j = 0; j < 4; j++) az[i][j] += a[i] * mm[j];
        }
        __syncthreads();
    }

    // ---- epilogue ----
    #pragma unroll
    for (int i = 0; i < 4; i++) {
        int t = t0 + tr * 4 + i;
        float4 ozg, osk;
        float* pz = &ozg.x; float* ps = &osk.x;
        #pragma unroll
        for (int j = 0; j < 4; j++) {
            int n = n0 + tc * 4 + j;
            float sig = 1.f / (1.f + expf(-(ago[i][j] + go_b[n])));
            float zv  = az[i][j] + mix_b[n];
            float sv  = ask[i][j] + skip_b[n];
            pz[j] = zv * sig;
            ps[j] = sv * (1.f - sig);
        }
        *(float4*)&zg [(size_t)t * OUT_DIM + n0 + tc * 4] = ozg;
        *(float4*)&sk2[(size_t)t * OUT_DIM + n0 + tc * 4] = osk;
    }
}

// ---------------- G3: LayerNorm + residual --------------------------------------------------
__global__ __launch_bounds__(256) void g3_ln(const float* __restrict__ zg,
        const float* __restrict__ sk2, float* __restrict__ out)
{
    __shared__ float sb[4], qb[4];
    __shared__ float mu_s, rstd_s;
    const int t = blockIdx.x;
    const int tid = threadIdx.x;
    float4 z4 = *(const float4*)&zg [(size_t)t * OUT_DIM + tid * 4];
    float4 s4 = *(const float4*)&sk2[(size_t)t * OUT_DIM + tid * 4];
    float s = z4.x + z4.y + z4.z + z4.w;
    float q = z4.x*z4.x + z4.y*z4.y + z4.z*z4.z + z4.w*z4.w;
    #pragma unroll
    for (int off = 32; off > 0; off >>= 1) {
        s += __shfl_down(s, off, 64);
        q += __shfl_down(q, off, 64);
    }
    int wid = tid >> 6;
    if ((tid & 63) == 0) { sb[wid] = s; qb[wid] = q; }
    __syncthreads();
    if (tid == 0) {
        float S = sb[0] + sb[1] + sb[2] + sb[3];
        float Q = qb[0] + qb[1] + qb[2] + qb[3];
        float mu = S * (1.f / 1024.f);
        float var = Q * (1.f / 1024.f) - mu * mu;
        mu_s = mu; rstd_s = rsqrtf(var + 1e-5f);
    }
    __syncthreads();
    float mu = mu_s, rs = rstd_s;
    float4 o;
    o.x = (z4.x - mu) * rs + s4.x;
    o.y = (z4.y - mu) * rs + s4.y;
    o.z = (z4.z - mu) * rs + s4.z;
    o.w = (z4.w - mu) * rs + s4.w;
    *(float4*)&out[(size_t)t * OUT_DIM + tid * 4] = o;
}

// ---------------- G4: final_state — planar (re[1024] then im[1024]), each write guarded -------
// Covers both harness conventions: real-part-only (out_size = 8388608+1024) and
// planar re/im (out_size = 8388608+2048). Interleaved was disproven in round 1.
__global__ void g4_final(const float* __restrict__ zinT, float* __restrict__ out, int out_size)
{
    int p = blockIdx.x * blockDim.x + threadIdx.x;  // 0..1023 = m*16+c
    if (p >= 1024) return;
    int m = p >> 4, c = p & 15;
    float re = zinT[(size_t)(m * 32 + c)      * T_DIM + T_DIM - 1];
    float im = zinT[(size_t)(m * 32 + 16 + c) * T_DIM + T_DIM - 1];
    long long base = (long long)T_DIM * OUT_DIM;
    if (base + p < (long long)out_size)        out[base + p]        = re;
    if (base + 1024 + p < (long long)out_size) out[base + 1024 + p] = im;
}

extern "C" void kernel_launch(void* const* d_in, const int* in_sizes, int n_in,
                              void* d_out, int out_size, void* d_ws, size_t ws_size,
                              hipStream_t stream) {
    const float* x        = (const float*)d_in[0];
    const float* state_re = (const float*)d_in[1];
    const float* state_im = (const float*)d_in[2];
    const void*  startp   = d_in[3];
    const float* pre_w    = (const float*)d_in[5];
    const float* pre_b    = (const float*)d_in[6];
    const float* gi_w     = (const float*)d_in[7];
    const float* gi_b     = (const float*)d_in[8];
    const float* go_w     = (const float*)d_in[9];
    const float* go_b     = (const float*)d_in[10];
    const float* skip_w   = (const float*)d_in[11];
    const float* skip_b   = (const float*)d_in[12];
    const float* mix_w    = (const float*)d_in[13];
    const float* mix_b    = (const float*)d_in[14];
    const float* ffa_a    = (const float*)d_in[15];
    const float* ffa_b    = (const float*)d_in[16];

    float* ws   = (float*)d_ws;
    float* gxT  = ws;
    float* zinT = ws + 524288;
    float* zg   = ws + 524288 + 16777216;
    float* sk2  = zg + 8388608;
    unsigned char* mask = (unsigned char*)(ws + 34078720);
    float* out  = (float*)d_out;

    hipLaunchKernelGGL(k0_start, dim3(1),    dim3(1024), 0, stream, startp, mask);
    hipLaunchKernelGGL(k1_gate,  dim3(256),  dim3(256),  0, stream, x, pre_w, pre_b, gi_w, gi_b, gxT);
    hipLaunchKernelGGL(k2_scan,  dim3(1024), dim3(128),  0, stream, gxT, mask, state_re, state_im, ffa_a, ffa_b, zinT);
    hipLaunchKernelGGL(g2_gemm,  dim3(2048), dim3(256),  0, stream, x, zinT, go_w, go_b, skip_w, skip_b, mix_w, mix_b, zg, sk2);
    hipLaunchKernelGGL(g3_ln,    dim3(8192), dim3(256),  0, stream, zg, sk2, out);
    hipLaunchKernelGGL(g4_final, dim3(4),    dim3(256),  0, stream, zinT, out, out_size);
}

// Round 3
// 460.249 us; speedup vs baseline: 2.5636x; 2.5636x over previous
//
#include <hip/hip_runtime.h>
#include <math.h>

#define T_DIM 8192
#define IN_DIM 1024
#define TRACE 64
#define CTX 16
#define OUT_DIM 1024
#define KMIX 2048

typedef __attribute__((ext_vector_type(8))) short bf16x8;
typedef __attribute__((ext_vector_type(4))) float f32x4;

__device__ __forceinline__ unsigned short f2bf(float f) {
    unsigned int u = __float_as_uint(f);
    u = (u + 0x7FFFu + ((u >> 16) & 1u)) >> 16;
    return (unsigned short)u;
}
__device__ __forceinline__ float bf2f(unsigned short b) {
    return __uint_as_float(((unsigned int)b) << 16);
}

// ---------------- ws layout (float offsets) ----------------
// gxT   fp32 [64][8192]      @ 0         (524288 f)
// zinTb bf16 [2048][8192]    @ 524288    (8388608 f)   k-major: k=m*32+c re, m*32+16+c im
// zinb  bf16 [8192][2048]    @ 8912896   (8388608 f)   t-major (transposed)
// xb    bf16 [8192][1024]    @ 17301504  (4194304 f)
// gob   bf16 [1024][1024]    @ 21495808  (524288 f)
// skb   bf16 [1024][1024]    @ 22020096  (524288 f)
// mixb  bf16 [1024][2048]    @ 22544384  (1048576 f)
// zg    bf16 [8192][1024]    @ 23592960  (4194304 f)
// sk2   bf16 [8192][1024]    @ 27787264  (4194304 f)
// fstate fp32 [2048]         @ 31981568  (2048 f)      re[1024], im[1024]
// mask  u8   [8192]          @ 31983616  (2048 f)
// total 31985664 floats = ~122 MB  (<= 130 MB proven available)

// ---------------- K0: normalize `start` to uint8 mask -----------------------------------------
__global__ void k0_start(const void* __restrict__ startp, unsigned char* __restrict__ mask)
{
    __shared__ int nonbool;
    int tid = threadIdx.x;              // 1024 threads
    if (tid == 0) nonbool = 0;
    __syncthreads();
    const unsigned int* w = (const unsigned int*)startp;
    unsigned int a = w[tid];
    unsigned int b = w[tid + 1024];
    if (a > 1u || b > 1u) nonbool = 1;
    __syncthreads();
    if (nonbool) {
        const unsigned char* s8 = (const unsigned char*)startp;
        for (int i = tid; i < T_DIM; i += 1024) mask[i] = (unsigned char)(s8[i] != 0);
    } else {
        const int* s32 = (const int*)startp;
        for (int i = tid; i < T_DIM; i += 1024) mask[i] = (unsigned char)(s32[i] != 0);
    }
}

// ---------------- C0: fp32 -> bf16 conversions (x, go_w, skip_w, mix_w) ------------------------
__global__ __launch_bounds__(256) void c0_conv(const float* __restrict__ x,
        const float* __restrict__ gw, const float* __restrict__ sw, const float* __restrict__ mw,
        unsigned short* __restrict__ xb, unsigned short* __restrict__ gob,
        unsigned short* __restrict__ skb, unsigned short* __restrict__ mixb)
{
    const size_t QX = 2097152, QG = 262144, QS = 262144, QM = 524288;  // quads (4 floats each)
    const size_t total = QX + QG + QS + QM;
    for (size_t q = (size_t)blockIdx.x * blockDim.x + threadIdx.x; q < total;
         q += (size_t)gridDim.x * blockDim.x) {
        const float* src; unsigned short* dst; size_t i;
        if (q < QX)            { src = x;  dst = xb;   i = q; }
        else if (q < QX+QG)    { src = gw; dst = gob;  i = q - QX; }
        else if (q < QX+QG+QS) { src = sw; dst = skb;  i = q - QX - QG; }
        else                   { src = mw; dst = mixb; i = q - QX - QG - QS; }
        float4 v = *(const float4*)(src + i * 4);
        ushort4 o;
        o.x = f2bf(v.x); o.y = f2bf(v.y); o.z = f2bf(v.z); o.w = f2bf(v.w);
        *(ushort4*)(dst + i * 4) = o;
    }
}

// ---------------- K1: gated_x = (x@pre_w.T+pre_b) * sigmoid(x@gi_w.T+gi_b) -> gxT[m][t] -------
__global__ __launch_bounds__(256) void k1_gate(const float* __restrict__ x,
        const float* __restrict__ pre_w, const float* __restrict__ pre_b,
        const float* __restrict__ gi_w,  const float* __restrict__ gi_b,
        float* __restrict__ gxT)
{
    __shared__ __align__(16) float xsT[64][36];
    __shared__ __align__(16) float wTp[64][68];
    __shared__ __align__(16) float wTg[64][68];
    __shared__ __align__(16) float sgbuf[32][68];

    const int tid = threadIdx.x;
    const int t0  = blockIdx.x * 32;
    const int sel = tid >> 7;
    const int tr  = (tid >> 4) & 7;
    const int tc  = tid & 15;

    float acc[4][4];
    #pragma unroll
    for (int i = 0; i < 4; i++)
        #pragma unroll
        for (int j = 0; j < 4; j++) acc[i][j] = 0.f;

    float (*wT)[68] = sel ? wTg : wTp;

    for (int k0 = 0; k0 < IN_DIM; k0 += 64) {
        {
            int lo = tid & 15, row = tid >> 4;
            #pragma unroll
            for (int p = 0; p < 2; p++) {
                int t = row + p * 16;
                float4 v = *(const float4*)&x[(size_t)(t0 + t) * IN_DIM + k0 + lo * 4];
                xsT[lo*4+0][t] = v.x; xsT[lo*4+1][t] = v.y;
                xsT[lo*4+2][t] = v.z; xsT[lo*4+3][t] = v.w;
            }
        }
        {
            int lo = tid & 15, row = tid >> 4;
            #pragma unroll
            for (int p = 0; p < 4; p++) {
                int m = row + p * 16;
                float4 v = *(const float4*)&pre_w[(size_t)m * IN_DIM + k0 + lo * 4];
                wTp[lo*4+0][m] = v.x; wTp[lo*4+1][m] = v.y;
                wTp[lo*4+2][m] = v.z; wTp[lo*4+3][m] = v.w;
                v = *(const float4*)&gi_w[(size_t)m * IN_DIM + k0 + lo * 4];
                wTg[lo*4+0][m] = v.x; wTg[lo*4+1][m] = v.y;
                wTg[lo*4+2][m] = v.z; wTg[lo*4+3][m] = v.w;
            }
        }
        __syncthreads();
        #pragma unroll 8
        for (int k = 0; k < 64; k++) {
            float4 a4 = *(const float4*)&xsT[k][tr * 4];
            float4 w4 = *(const float4*)&wT[k][tc * 4];
            float a[4] = {a4.x, a4.y, a4.z, a4.w};
            float wv[4] = {w4.x, w4.y, w4.z, w4.w};
            #pragma unroll
            for (int i = 0; i < 4; i++)
                #pragma unroll
                for (int j = 0; j < 4; j++) acc[i][j] += a[i] * wv[j];
        }
        __syncthreads();
    }

    if (sel == 1) {
        #pragma unroll
        for (int i = 0; i < 4; i++)
            #pragma unroll
            for (int j = 0; j < 4; j++) {
                int m = tc * 4 + j;
                sgbuf[tr * 4 + i][m] = 1.f / (1.f + expf(-(acc[i][j] + gi_b[m])));
            }
    }
    __syncthreads();
    if (sel == 0) {
        #pragma unroll
        for (int j = 0; j < 4; j++) {
            int m = tc * 4 + j;
            float b = pre_b[m];
            float4 o;
            o.x = (acc[0][j] + b) * sgbuf[tr*4+0][m];
            o.y = (acc[1][j] + b) * sgbuf[tr*4+1][m];
            o.z = (acc[2][j] + b) * sgbuf[tr*4+2][m];
            o.w = (acc[3][j] + b) * sgbuf[tr*4+3][m];
            *(float4*)&gxT[(size_t)m * T_DIM + t0 + tr * 4] = o;
        }
    }
}

// ---------------- K2: resettable complex scan -> zinTb (bf16, K-major) + fstate (fp32) --------
__global__ __launch_bounds__(128) void k2_scan(const float* __restrict__ gxT,
        const unsigned char* __restrict__ mask8,
        const float* __restrict__ state_re, const float* __restrict__ state_im,
        const float* __restrict__ ffa_a, const float* __restrict__ ffa_b,
        unsigned short* __restrict__ zinTb, float* __restrict__ fstate)
{
    const int m = blockIdx.x >> 4;
    const int c = blockIdx.x & 15;
    const int j = threadIdx.x;
    __shared__ float Br[128], Bi[128], Er[128], Ei[128];
    __shared__ unsigned char Rf[128];

    const float am = -fabsf(ffa_a[m]);
    const float bc = ffa_b[c];
    const float er = expf(am);
    const float gr = er * cosf(bc);
    const float gi = er * sinf(bc);

    const float* gx = gxT + (size_t)m * T_DIM;
    const int t0 = j * 64;

    unsigned long long rmask = 0ull;
    float sre = 0.f, sim = 0.f;
    bool r = false;
    for (int i = 0; i < 64; i++) {
        int t = t0 + i;
        if (mask8[t]) { rmask |= 1ull << i; sre = 0.f; sim = 0.f; r = true; }
        else { float tr_ = sre * gr - sim * gi; sim = sre * gi + sim * gr; sre = tr_; }
        sre += gx[t];
    }
    Br[j] = sre; Bi[j] = sim; Rf[j] = r ? 1 : 0;
    __syncthreads();
    if (j == 0) {
        float e64  = expf(64.f * am);
        float g64r = e64 * cosf(64.f * bc);
        float g64i = e64 * sinf(64.f * bc);
        float pr = state_re[m * CTX + c], pi = state_im[m * CTX + c];
        for (int q = 0; q < 128; q++) {
            Er[q] = pr; Ei[q] = pi;
            if (Rf[q]) { pr = Br[q]; pi = Bi[q]; }
            else {
                float nr = pr * g64r - pi * g64i + Br[q];
                pi       = pr * g64i + pi * g64r + Bi[q];
                pr = nr;
            }
        }
    }
    __syncthreads();
    sre = Er[j]; sim = Ei[j];
    unsigned short* zreb = zinTb + (size_t)(m * 32 + c)      * T_DIM;
    unsigned short* zimb = zinTb + (size_t)(m * 32 + 16 + c) * T_DIM;
    for (int i = 0; i < 64; i++) {
        int t = t0 + i;
        if (rmask & (1ull << i)) { sre = 0.f; sim = 0.f; }
        else { float tr_ = sre * gr - sim * gi; sim = sre * gi + sim * gr; sre = tr_; }
        sre += gx[t];
        zreb[t] = f2bf(sre); zimb[t] = f2bf(sim);
    }
    if (j == 127) {  // exact fp32 final state (t = 8191)
        int p = m * CTX + c;
        fstate[p]        = sre;
        fstate[1024 + p] = sim;
    }
}

// ---------------- T3: transpose zinTb[k][t] (bf16) -> zinb[t][k] (bf16), 64x64 tiles ----------
__global__ __launch_bounds__(256) void t3_tr(const unsigned short* __restrict__ zinTb,
                                             unsigned short* __restrict__ zinb)
{
    __shared__ unsigned short S[64][72];
    const int k0 = blockIdx.x * 64, t0 = blockIdx.y * 64;
    const int tid = threadIdx.x;
    {
        int kr = tid >> 3, tc = (tid & 7) * 8;
        #pragma unroll
        for (int p = 0; p < 2; p++) {
            int k = kr + p * 32;
            ushort4 a = *(const ushort4*)&zinTb[(size_t)(k0 + k) * T_DIM + t0 + tc];
            ushort4 b = *(const ushort4*)&zinTb[(size_t)(k0 + k) * T_DIM + t0 + tc + 4];
            *(ushort4*)&S[k][tc]     = a;
            *(ushort4*)&S[k][tc + 4] = b;
        }
    }
    __syncthreads();
    {
        int tr = tid >> 3, kc = (tid & 7) * 8;
        #pragma unroll
        for (int p = 0; p < 2; p++) {
            int t = tr + p * 32;
            ushort4 o1, o2;
            o1.x = S[kc+0][t]; o1.y = S[kc+1][t]; o1.z = S[kc+2][t]; o1.w = S[kc+3][t];
            o2.x = S[kc+4][t]; o2.y = S[kc+5][t]; o2.z = S[kc+6][t]; o2.w = S[kc+7][t];
            *(ushort4*)&zinb[(size_t)(t0 + t) * KMIX + k0 + kc]     = o1;
            *(ushort4*)&zinb[(size_t)(t0 + t) * KMIX + k0 + kc + 4] = o2;
        }
    }
}

// ---------------- MFMA K-loop helper: 128x128 tile, BK=32, 16x16x32 bf16 ----------------------
__device__ __forceinline__ void mfma_loop(const unsigned short* __restrict__ A, int lda,
        const unsigned short* __restrict__ B, int ldb, int K,
        int t0, int n0, int tid, int wm, int wn, int quad, int l16,
        unsigned short (*As)[40], unsigned short (*Bs)[40], f32x4 (*acc)[4])
{
    const int r = tid >> 2, c = (tid & 3) * 8;
    for (int k0 = 0; k0 < K; k0 += 32) {
        float4 va0 = *(const float4*)(A + (size_t)(t0 + r)      * lda + k0 + c);
        float4 va1 = *(const float4*)(A + (size_t)(t0 + r + 64) * lda + k0 + c);
        float4 vb0 = *(const float4*)(B + (size_t)(n0 + r)      * ldb + k0 + c);
        float4 vb1 = *(const float4*)(B + (size_t)(n0 + r + 64) * ldb + k0 + c);
        __syncthreads();   // prior iter's frag reads done before overwrite
        *(float4*)&As[r][c]      = va0;
        *(float4*)&As[r + 64][c] = va1;
        *(float4*)&Bs[r][c]      = vb0;
        *(float4*)&Bs[r + 64][c] = vb1;
        __syncthreads();
        bf16x8 af[4], bf[4];
        #pragma unroll
        for (int mi = 0; mi < 4; mi++)
            af[mi] = *(const bf16x8*)&As[wm * 64 + mi * 16 + l16][quad * 8];
        #pragma unroll
        for (int ni = 0; ni < 4; ni++)
            bf[ni] = *(const bf16x8*)&Bs[wn * 64 + ni * 16 + l16][quad * 8];
        #pragma unroll
        for (int mi = 0; mi < 4; mi++)
            #pragma unroll
            for (int ni = 0; ni < 4; ni++)
                acc[mi][ni] = __builtin_amdgcn_mfma_f32_16x16x32_bf16(af[mi], bf[ni], acc[mi][ni], 0, 0, 0);
    }
}

// ---------------- GA: go -> sigmoid; skip -> sk2; mix -> zg (all bf16 MFMA, fused gating) ------
__global__ __launch_bounds__(256) void gA_gemm(
        const unsigned short* __restrict__ xb,   const unsigned short* __restrict__ zinb,
        const unsigned short* __restrict__ gob,  const unsigned short* __restrict__ skb,
        const unsigned short* __restrict__ mixb,
        const float* __restrict__ go_b, const float* __restrict__ skip_b, const float* __restrict__ mix_b,
        unsigned short* __restrict__ zg, unsigned short* __restrict__ sk2)
{
    __shared__ unsigned short As[128][40];
    __shared__ unsigned short Bs[128][40];
    const int tid = threadIdx.x;
    const int n0 = blockIdx.x * 128, t0 = blockIdx.y * 128;
    const int lane = tid & 63, w = tid >> 6;
    const int wm = w >> 1, wn = w & 1;
    const int quad = lane >> 4, l16 = lane & 15;

    f32x4 acc[4][4];
    const f32x4 zero4 = {0.f, 0.f, 0.f, 0.f};

    // ---- phase 1: go gate ----
    #pragma unroll
    for (int mi = 0; mi < 4; mi++)
        #pragma unroll
        for (int ni = 0; ni < 4; ni++) acc[mi][ni] = zero4;
    mfma_loop(xb, IN_DIM, gob, IN_DIM, IN_DIM, t0, n0, tid, wm, wn, quad, l16, As, Bs, acc);

    unsigned int sigp[32];
    #pragma unroll
    for (int mi = 0; mi < 4; mi++)
        #pragma unroll
        for (int ni = 0; ni < 4; ni++) {
            float gb = go_b[n0 + wn * 64 + ni * 16 + l16];
            #pragma unroll
            for (int r2 = 0; r2 < 2; r2++) {
                float s0 = 1.f / (1.f + expf(-(acc[mi][ni][r2 * 2]     + gb)));
                float s1 = 1.f / (1.f + expf(-(acc[mi][ni][r2 * 2 + 1] + gb)));
                sigp[(mi * 4 + ni) * 2 + r2] =
                    (unsigned int)f2bf(s0) | ((unsigned int)f2bf(s1) << 16);
            }
        }

    // ---- phase 2: skip -> sk2 = (skip+skip_b)*(1-sig) ----
    #pragma unroll
    for (int mi = 0; mi < 4; mi++)
        #pragma unroll
        for (int ni = 0; ni < 4; ni++) acc[mi][ni] = zero4;
    mfma_loop(xb, IN_DIM, skb, IN_DIM, IN_DIM, t0, n0, tid, wm, wn, quad, l16, As, Bs, acc);

    #pragma unroll
    for (int mi = 0; mi < 4; mi++)
        #pragma unroll
        for (int ni = 0; ni < 4; ni++) {
            int n = n0 + wn * 64 + ni * 16 + l16;
            float sb_ = skip_b[n];
            #pragma unroll
            for (int rr = 0; rr < 4; rr++) {
                unsigned int u = sigp[(mi * 4 + ni) * 2 + (rr >> 1)];
                float sig = bf2f((unsigned short)((rr & 1) ? (u >> 16) : (u & 0xffff)));
                float v = (acc[mi][ni][rr] + sb_) * (1.f - sig);
                int t = t0 + wm * 64 + mi * 16 + quad * 4 + rr;
                sk2[(size_t)t * OUT_DIM + n] = f2bf(v);
            }
        }

    // ---- phase 3: mix -> zg = (z+mix_b)*sig ----
    #pragma unroll
    for (int mi = 0; mi < 4; mi++)
        #pragma unroll
        for (int ni = 0; ni < 4; ni++) acc[mi][ni] = zero4;
    mfma_loop(zinb, KMIX, mixb, KMIX, KMIX, t0, n0, tid, wm, wn, quad, l16, As, Bs, acc);

    #pragma unroll
    for (int mi = 0; mi < 4; mi++)
        #pragma unroll
        for (int ni = 0; ni < 4; ni++) {
            int n = n0 + wn * 64 + ni * 16 + l16;
            float mb_ = mix_b[n];
            #pragma unroll
            for (int rr = 0; rr < 4; rr++) {
                unsigned int u = sigp[(mi * 4 + ni) * 2 + (rr >> 1)];
                float sig = bf2f((unsigned short)((rr & 1) ? (u >> 16) : (u & 0xffff)));
                float v = (acc[mi][ni][rr] + mb_) * sig;
                int t = t0 + wm * 64 + mi * 16 + quad * 4 + rr;
                zg[(size_t)t * OUT_DIM + n] = f2bf(v);
            }
        }
}

// ---------------- G3: LayerNorm + residual (bf16 in, fp32 out) --------------------------------
__global__ __launch_bounds__(256) void g3_ln(const unsigned short* __restrict__ zg,
        const unsigned short* __restrict__ sk2, float* __restrict__ out)
{
    __shared__ float sb[4], qb[4];
    __shared__ float mu_s, rstd_s;
    const int t = blockIdx.x;
    const int tid = threadIdx.x;
    ushort4 zu = *(const ushort4*)&zg [(size_t)t * OUT_DIM + tid * 4];
    ushort4 su = *(const ushort4*)&sk2[(size_t)t * OUT_DIM + tid * 4];
    float z0 = bf2f(zu.x), z1 = bf2f(zu.y), z2 = bf2f(zu.z), z3 = bf2f(zu.w);
    float s0 = bf2f(su.x), s1 = bf2f(su.y), s2 = bf2f(su.z), s3 = bf2f(su.w);
    float s = z0 + z1 + z2 + z3;
    float q = z0*z0 + z1*z1 + z2*z2 + z3*z3;
    #pragma unroll
    for (int off = 32; off > 0; off >>= 1) {
        s += __shfl_down(s, off, 64);
        q += __shfl_down(q, off, 64);
    }
    int wid = tid >> 6;
    if ((tid & 63) == 0) { sb[wid] = s; qb[wid] = q; }
    __syncthreads();
    if (tid == 0) {
        float S = sb[0] + sb[1] + sb[2] + sb[3];
        float Q = qb[0] + qb[1] + qb[2] + qb[3];
        float mu = S * (1.f / 1024.f);
        float var = Q * (1.f / 1024.f) - mu * mu;
        mu_s = mu; rstd_s = rsqrtf(var + 1e-5f);
    }
    __syncthreads();
    float mu = mu_s, rs = rstd_s;
    float4 o;
    o.x = (z0 - mu) * rs + s0;
    o.y = (z1 - mu) * rs + s1;
    o.z = (z2 - mu) * rs + s2;
    o.w = (z3 - mu) * rs + s3;
    *(float4*)&out[(size_t)t * OUT_DIM + tid * 4] = o;
}

// ---------------- G4: final_state copy (planar re/im, guarded — round-2-proven layout) --------
__global__ void g4_final(const float* __restrict__ fstate, float* __restrict__ out, int out_size)
{
    int i = blockIdx.x * blockDim.x + threadIdx.x;
    if (i >= 2048) return;
    long long base = (long long)T_DIM * OUT_DIM;
    if (base + i < (long long)out_size) out[base + i] = fstate[i];
}

extern "C" void kernel_launch(void* const* d_in, const int* in_sizes, int n_in,
                              void* d_out, int out_size, void* d_ws, size_t ws_size,
                              hipStream_t stream) {
    const float* x        = (const float*)d_in[0];
    const float* state_re = (const float*)d_in[1];
    const float* state_im = (const float*)d_in[2];
    const void*  startp   = d_in[3];
    const float* pre_w    = (const float*)d_in[5];
    const float* pre_b    = (const float*)d_in[6];
    const float* gi_w     = (const float*)d_in[7];
    const float* gi_b     = (const float*)d_in[8];
    const float* go_w     = (const float*)d_in[9];
    const float* go_b     = (const float*)d_in[10];
    const float* skip_w   = (const float*)d_in[11];
    const float* skip_b   = (const float*)d_in[12];
    const float* mix_w    = (const float*)d_in[13];
    const float* mix_b    = (const float*)d_in[14];
    const float* ffa_a    = (const float*)d_in[15];
    const float* ffa_b    = (const float*)d_in[16];

    float* ws = (float*)d_ws;
    float*          gxT    = ws;                                    // 524288 f
    unsigned short* zinTb  = (unsigned short*)(ws + 524288);        // 16777216 us
    unsigned short* zinb   = (unsigned short*)(ws + 8912896);       // 16777216 us
    unsigned short* xb     = (unsigned short*)(ws + 17301504);      // 8388608 us
    unsigned short* gob    = (unsigned short*)(ws + 21495808);      // 1048576 us
    unsigned short* skb    = (unsigned short*)(ws + 22020096);      // 1048576 us
    unsigned short* mixb   = (unsigned short*)(ws + 22544384);      // 2097152 us
    unsigned short* zg     = (unsigned short*)(ws + 23592960);      // 8388608 us
    unsigned short* sk2    = (unsigned short*)(ws + 27787264);      // 8388608 us
    float*          fstate = ws + 31981568;                         // 2048 f
    unsigned char*  mask   = (unsigned char*)(ws + 31983616);       // 8192 B
    float* out = (float*)d_out;

    hipLaunchKernelGGL(k0_start, dim3(1),          dim3(1024), 0, stream, startp, mask);
    hipLaunchKernelGGL(c0_conv,  dim3(1536),       dim3(256),  0, stream, x, go_w, skip_w, mix_w, xb, gob, skb, mixb);
    hipLaunchKernelGGL(k1_gate,  dim3(256),        dim3(256),  0, stream, x, pre_w, pre_b, gi_w, gi_b, gxT);
    hipLaunchKernelGGL(k2_scan,  dim3(1024),       dim3(128),  0, stream, gxT, mask, state_re, state_im, ffa_a, ffa_b, zinTb, fstate);
    hipLaunchKernelGGL(t3_tr,    dim3(32, 128),    dim3(256),  0, stream, zinTb, zinb);
    hipLaunchKernelGGL(gA_gemm,  dim3(8, 64),      dim3(256),  0, stream, xb, zinb, gob, skb, mixb, go_b, skip_b, mix_b, zg, sk2);
    hipLaunchKernelGGL(g3_ln,    dim3(8192),       dim3(256),  0, stream, zg, sk2, out);
    hipLaunchKernelGGL(g4_final, dim3(8),          dim3(256),  0, stream, fstate, out, out_size);
}

// Round 4
// 368.649 us; speedup vs baseline: 3.2006x; 1.2485x over previous
//
#include <hip/hip_runtime.h>
#include <math.h>

#define T_DIM 8192
#define IN_DIM 1024
#define TRACE 64
#define CTX 16
#define OUT_DIM 1024
#define KMIX 2048

typedef __attribute__((ext_vector_type(8))) short bf16x8;
typedef __attribute__((ext_vector_type(4))) float f32x4;

__device__ __forceinline__ unsigned short f2bf(float f) {
    unsigned int u = __float_as_uint(f);
    u = (u + 0x7FFFu + ((u >> 16) & 1u)) >> 16;
    return (unsigned short)u;
}
__device__ __forceinline__ float bf2f(unsigned short b) {
    return __uint_as_float(((unsigned int)b) << 16);
}

__device__ __forceinline__ void gl2lds16(const void* g, void* l) {
    __builtin_amdgcn_global_load_lds(
        (const __attribute__((address_space(1))) unsigned int*)g,
        (__attribute__((address_space(3))) unsigned int*)l,
        16, 0, 0);
}

// ---------------- ws layout (float offsets) ----------------
// gxT   fp32 [64][8192]      @ 0         (524288 f)
// zinTb bf16 [2048][8192]    @ 524288    (8388608 f)   k-major: k=m*32+c re, m*32+16+c im
// zinb  bf16 [8192][2048]    @ 8912896   (8388608 f)   t-major (transposed)
// xb    bf16 [8192][1024]    @ 17301504  (4194304 f)
// gob   bf16 [1024][1024]    @ 21495808  (524288 f)
// skb   bf16 [1024][1024]    @ 22020096  (524288 f)
// mixb  bf16 [1024][2048]    @ 22544384  (1048576 f)
// zg    bf16 [8192][1024]    @ 23592960  (4194304 f)
// sk2   bf16 [8192][1024]    @ 27787264  (4194304 f)
// fstate fp32 [2048]         @ 31981568  (2048 f)
// mask  u8   [8192]          @ 31983616  (2048 f)

// ---------------- K0: normalize `start` to uint8 mask -----------------------------------------
__global__ void k0_start(const void* __restrict__ startp, unsigned char* __restrict__ mask)
{
    __shared__ int nonbool;
    int tid = threadIdx.x;
    if (tid == 0) nonbool = 0;
    __syncthreads();
    const unsigned int* w = (const unsigned int*)startp;
    unsigned int a = w[tid];
    unsigned int b = w[tid + 1024];
    if (a > 1u || b > 1u) nonbool = 1;
    __syncthreads();
    if (nonbool) {
        const unsigned char* s8 = (const unsigned char*)startp;
        for (int i = tid; i < T_DIM; i += 1024) mask[i] = (unsigned char)(s8[i] != 0);
    } else {
        const int* s32 = (const int*)startp;
        for (int i = tid; i < T_DIM; i += 1024) mask[i] = (unsigned char)(s32[i] != 0);
    }
}

// ---------------- C0: fp32 -> bf16 conversions (x, go_w, skip_w, mix_w) ------------------------
__global__ __launch_bounds__(256) void c0_conv(const float* __restrict__ x,
        const float* __restrict__ gw, const float* __restrict__ sw, const float* __restrict__ mw,
        unsigned short* __restrict__ xb, unsigned short* __restrict__ gob,
        unsigned short* __restrict__ skb, unsigned short* __restrict__ mixb)
{
    const size_t QX = 2097152, QG = 262144, QS = 262144, QM = 524288;
    const size_t total = QX + QG + QS + QM;
    for (size_t q = (size_t)blockIdx.x * blockDim.x + threadIdx.x; q < total;
         q += (size_t)gridDim.x * blockDim.x) {
        const float* src; unsigned short* dst; size_t i;
        if (q < QX)            { src = x;  dst = xb;   i = q; }
        else if (q < QX+QG)    { src = gw; dst = gob;  i = q - QX; }
        else if (q < QX+QG+QS) { src = sw; dst = skb;  i = q - QX - QG; }
        else                   { src = mw; dst = mixb; i = q - QX - QG - QS; }
        float4 v = *(const float4*)(src + i * 4);
        ushort4 o;
        o.x = f2bf(v.x); o.y = f2bf(v.y); o.z = f2bf(v.z); o.w = f2bf(v.w);
        *(ushort4*)(dst + i * 4) = o;
    }
}

// ---------------- K1: gated_x = (x@pre_w.T+pre_b) * sigmoid(x@gi_w.T+gi_b) -> gxT[m][t] -------
__global__ __launch_bounds__(256) void k1_gate(const float* __restrict__ x,
        const float* __restrict__ pre_w, const float* __restrict__ pre_b,
        const float* __restrict__ gi_w,  const float* __restrict__ gi_b,
        float* __restrict__ gxT)
{
    __shared__ __align__(16) float xsT[64][36];
    __shared__ __align__(16) float wTp[64][68];
    __shared__ __align__(16) float wTg[64][68];
    __shared__ __align__(16) float sgbuf[32][68];

    const int tid = threadIdx.x;
    const int t0  = blockIdx.x * 32;
    const int sel = tid >> 7;
    const int tr  = (tid >> 4) & 7;
    const int tc  = tid & 15;

    float acc[4][4];
    #pragma unroll
    for (int i = 0; i < 4; i++)
        #pragma unroll
        for (int j = 0; j < 4; j++) acc[i][j] = 0.f;

    float (*wT)[68] = sel ? wTg : wTp;

    for (int k0 = 0; k0 < IN_DIM; k0 += 64) {
        {
            int lo = tid & 15, row = tid >> 4;
            #pragma unroll
            for (int p = 0; p < 2; p++) {
                int t = row + p * 16;
                float4 v = *(const float4*)&x[(size_t)(t0 + t) * IN_DIM + k0 + lo * 4];
                xsT[lo*4+0][t] = v.x; xsT[lo*4+1][t] = v.y;
                xsT[lo*4+2][t] = v.z; xsT[lo*4+3][t] = v.w;
            }
        }
        {
            int lo = tid & 15, row = tid >> 4;
            #pragma unroll
            for (int p = 0; p < 4; p++) {
                int m = row + p * 16;
                float4 v = *(const float4*)&pre_w[(size_t)m * IN_DIM + k0 + lo * 4];
                wTp[lo*4+0][m] = v.x; wTp[lo*4+1][m] = v.y;
                wTp[lo*4+2][m] = v.z; wTp[lo*4+3][m] = v.w;
                v = *(const float4*)&gi_w[(size_t)m * IN_DIM + k0 + lo * 4];
                wTg[lo*4+0][m] = v.x; wTg[lo*4+1][m] = v.y;
                wTg[lo*4+2][m] = v.z; wTg[lo*4+3][m] = v.w;
            }
        }
        __syncthreads();
        #pragma unroll 8
        for (int k = 0; k < 64; k++) {
            float4 a4 = *(const float4*)&xsT[k][tr * 4];
            float4 w4 = *(const float4*)&wT[k][tc * 4];
            float a[4] = {a4.x, a4.y, a4.z, a4.w};
            float wv[4] = {w4.x, w4.y, w4.z, w4.w};
            #pragma unroll
            for (int i = 0; i < 4; i++)
                #pragma unroll
                for (int j = 0; j < 4; j++) acc[i][j] += a[i] * wv[j];
        }
        __syncthreads();
    }

    if (sel == 1) {
        #pragma unroll
        for (int i = 0; i < 4; i++)
            #pragma unroll
            for (int j = 0; j < 4; j++) {
                int m = tc * 4 + j;
                sgbuf[tr * 4 + i][m] = 1.f / (1.f + expf(-(acc[i][j] + gi_b[m])));
            }
    }
    __syncthreads();
    if (sel == 0) {
        #pragma unroll
        for (int j = 0; j < 4; j++) {
            int m = tc * 4 + j;
            float b = pre_b[m];
            float4 o;
            o.x = (acc[0][j] + b) * sgbuf[tr*4+0][m];
            o.y = (acc[1][j] + b) * sgbuf[tr*4+1][m];
            o.z = (acc[2][j] + b) * sgbuf[tr*4+2][m];
            o.w = (acc[3][j] + b) * sgbuf[tr*4+3][m];
            *(float4*)&gxT[(size_t)m * T_DIM + t0 + tr * 4] = o;
        }
    }
}

// ---------------- K2: resettable complex scan -> zinTb (bf16) + fstate (fp32) ------------------
// Register-buffered output: 8x16B burst stores per stream (kills the 8x write amplification).
__global__ __launch_bounds__(128) void k2_scan(const float* __restrict__ gxT,
        const unsigned char* __restrict__ mask8,
        const float* __restrict__ state_re, const float* __restrict__ state_im,
        const float* __restrict__ ffa_a, const float* __restrict__ ffa_b,
        unsigned short* __restrict__ zinTb, float* __restrict__ fstate)
{
    const int m = blockIdx.x >> 4;
    const int c = blockIdx.x & 15;
    const int j = threadIdx.x;
    __shared__ float Br[128], Bi[128], Er[128], Ei[128];
    __shared__ unsigned char Rf[128];

    const float am = -fabsf(ffa_a[m]);
    const float bc = ffa_b[c];
    const float er = expf(am);
    const float gr = er * cosf(bc);
    const float gi = er * sinf(bc);

    const float* gx = gxT + (size_t)m * T_DIM;
    const int t0 = j * 64;

    unsigned long long rmask = 0ull;
    float sre = 0.f, sim = 0.f;
    bool r = false;
    #pragma unroll 8
    for (int i = 0; i < 64; i++) {
        int t = t0 + i;
        if (mask8[t]) { rmask |= 1ull << i; sre = 0.f; sim = 0.f; r = true; }
        else { float tr_ = sre * gr - sim * gi; sim = sre * gi + sim * gr; sre = tr_; }
        sre += gx[t];
    }
    Br[j] = sre; Bi[j] = sim; Rf[j] = r ? 1 : 0;
    __syncthreads();
    if (j == 0) {
        float e64  = expf(64.f * am);
        float g64r = e64 * cosf(64.f * bc);
        float g64i = e64 * sinf(64.f * bc);
        float pr = state_re[m * CTX + c], pi = state_im[m * CTX + c];
        for (int q = 0; q < 128; q++) {
            Er[q] = pr; Ei[q] = pi;
            if (Rf[q]) { pr = Br[q]; pi = Bi[q]; }
            else {
                float nr = pr * g64r - pi * g64i + Br[q];
                pi       = pr * g64i + pi * g64r + Bi[q];
                pr = nr;
            }
        }
    }
    __syncthreads();
    sre = Er[j]; sim = Ei[j];
    unsigned int ore[32], oim[32];
    #pragma unroll
    for (int i = 0; i < 64; i++) {
        int t = t0 + i;
        if (rmask & (1ull << i)) { sre = 0.f; sim = 0.f; }
        else { float tr_ = sre * gr - sim * gi; sim = sre * gi + sim * gr; sre = tr_; }
        sre += gx[t];
        unsigned short hr = f2bf(sre), hi_ = f2bf(sim);
        if (i & 1) { ore[i >> 1] |= ((unsigned int)hr) << 16; oim[i >> 1] |= ((unsigned int)hi_) << 16; }
        else       { ore[i >> 1]  = hr;                        oim[i >> 1]  = hi_; }
    }
    unsigned short* zreb = zinTb + (size_t)(m * 32 + c)      * T_DIM;
    unsigned short* zimb = zinTb + (size_t)(m * 32 + 16 + c) * T_DIM;
    uint4* pre4 = (uint4*)(zreb + t0);
    uint4* pim4 = (uint4*)(zimb + t0);
    #pragma unroll
    for (int q = 0; q < 8; q++) pre4[q] = *(uint4*)&ore[q * 4];
    #pragma unroll
    for (int q = 0; q < 8; q++) pim4[q] = *(uint4*)&oim[q * 4];

    if (j == 127) {
        int p = m * CTX + c;
        fstate[p]        = sre;
        fstate[1024 + p] = sim;
    }
}

// ---------------- T3: transpose zinTb[k][t] -> zinb[t][k], 64x64 tiles -------------------------
__global__ __launch_bounds__(256) void t3_tr(const unsigned short* __restrict__ zinTb,
                                             unsigned short* __restrict__ zinb)
{
    __shared__ unsigned short S[64][72];
    const int k0 = blockIdx.x * 64, t0 = blockIdx.y * 64;
    const int tid = threadIdx.x;
    {
        int kr = tid >> 3, tc = (tid & 7) * 8;
        #pragma unroll
        for (int p = 0; p < 2; p++) {
            int k = kr + p * 32;
            ushort4 a = *(const ushort4*)&zinTb[(size_t)(k0 + k) * T_DIM + t0 + tc];
            ushort4 b = *(const ushort4*)&zinTb[(size_t)(k0 + k) * T_DIM + t0 + tc + 4];
            *(ushort4*)&S[k][tc]     = a;
            *(ushort4*)&S[k][tc + 4] = b;
        }
    }
    __syncthreads();
    {
        int tr = tid >> 3, kc = (tid & 7) * 8;
        #pragma unroll
        for (int p = 0; p < 2; p++) {
            int t = tr + p * 32;
            ushort4 o1, o2;
            o1.x = S[kc+0][t]; o1.y = S[kc+1][t]; o1.z = S[kc+2][t]; o1.w = S[kc+3][t];
            o2.x = S[kc+4][t]; o2.y = S[kc+5][t]; o2.z = S[kc+6][t]; o2.w = S[kc+7][t];
            *(ushort4*)&zinb[(size_t)(t0 + t) * KMIX + k0 + kc]     = o1;
            *(ushort4*)&zinb[(size_t)(t0 + t) * KMIX + k0 + kc + 4] = o2;
        }
    }
}

// ---------------- MFMA K-loop: 128x128 tile, BK=32, global_load_lds width=16 (m97 style) ------
// As/Bs: unpadded [128][32] bf16 flat (8 KB each). Thread tid stages 16B at LDS byte tid*16
// (wave-uniform base + lane*16 — the global_load_lds constraint).
__device__ __forceinline__ void mfma_loop(const unsigned short* __restrict__ A,
        const unsigned short* __restrict__ B, int ld, int K,
        int t0, int n0, int tid, int wm, int wn, int quad, int l16,
        unsigned short* As, unsigned short* Bs, f32x4 (*acc)[4])
{
    const int r = tid >> 2;
    const int c = (tid & 3) * 8;
    const unsigned short* gA0 = A + (size_t)(t0 + r)      * ld + c;
    const unsigned short* gA1 = A + (size_t)(t0 + 64 + r) * ld + c;
    const unsigned short* gB0 = B + (size_t)(n0 + r)      * ld + c;
    const unsigned short* gB1 = B + (size_t)(n0 + 64 + r) * ld + c;
    unsigned short* lA0 = As + tid * 8;
    unsigned short* lA1 = As + 2048 + tid * 8;
    unsigned short* lB0 = Bs + tid * 8;
    unsigned short* lB1 = Bs + 2048 + tid * 8;

    for (int k0 = 0; k0 < K; k0 += 32) {
        __syncthreads();                       // all waves done reading prev LDS tile
        gl2lds16(gA0 + k0, lA0);
        gl2lds16(gA1 + k0, lA1);
        gl2lds16(gB0 + k0, lB0);
        gl2lds16(gB1 + k0, lB1);
        asm volatile("s_waitcnt vmcnt(0)" ::: "memory");
        __syncthreads();
        bf16x8 af[4], bf[4];
        #pragma unroll
        for (int mi = 0; mi < 4; mi++)
            af[mi] = *(const bf16x8*)&As[(wm * 64 + mi * 16 + l16) * 32 + quad * 8];
        #pragma unroll
        for (int ni = 0; ni < 4; ni++)
            bf[ni] = *(const bf16x8*)&Bs[(wn * 64 + ni * 16 + l16) * 32 + quad * 8];
        #pragma unroll
        for (int mi = 0; mi < 4; mi++)
            #pragma unroll
            for (int ni = 0; ni < 4; ni++)
                acc[mi][ni] = __builtin_amdgcn_mfma_f32_16x16x32_bf16(af[mi], bf[ni], acc[mi][ni], 0, 0, 0);
    }
}

// ---------------- GA: go -> sigmoid; skip -> sk2; mix -> zg (bf16 MFMA, fused gating) ----------
__global__ __launch_bounds__(256) void gA_gemm(
        const unsigned short* __restrict__ xb,   const unsigned short* __restrict__ zinb,
        const unsigned short* __restrict__ gob,  const unsigned short* __restrict__ skb,
        const unsigned short* __restrict__ mixb,
        const float* __restrict__ go_b, const float* __restrict__ skip_b, const float* __restrict__ mix_b,
        unsigned short* __restrict__ zg, unsigned short* __restrict__ sk2)
{
    __shared__ __align__(16) unsigned short As[4096];
    __shared__ __align__(16) unsigned short Bs[4096];
    const int tid = threadIdx.x;
    const int n0 = blockIdx.x * 128, t0 = blockIdx.y * 128;
    const int lane = tid & 63, w = tid >> 6;
    const int wm = w >> 1, wn = w & 1;
    const int quad = lane >> 4, l16 = lane & 15;

    f32x4 acc[4][4];
    const f32x4 zero4 = {0.f, 0.f, 0.f, 0.f};

    // ---- phase 1: go gate ----
    #pragma unroll
    for (int mi = 0; mi < 4; mi++)
        #pragma unroll
        for (int ni = 0; ni < 4; ni++) acc[mi][ni] = zero4;
    mfma_loop(xb, gob, IN_DIM, IN_DIM, t0, n0, tid, wm, wn, quad, l16, As, Bs, acc);

    unsigned int sigp[32];
    #pragma unroll
    for (int mi = 0; mi < 4; mi++)
        #pragma unroll
        for (int ni = 0; ni < 4; ni++) {
            float gb = go_b[n0 + wn * 64 + ni * 16 + l16];
            #pragma unroll
            for (int r2 = 0; r2 < 2; r2++) {
                float s0 = 1.f / (1.f + expf(-(acc[mi][ni][r2 * 2]     + gb)));
                float s1 = 1.f / (1.f + expf(-(acc[mi][ni][r2 * 2 + 1] + gb)));
                sigp[(mi * 4 + ni) * 2 + r2] =
                    (unsigned int)f2bf(s0) | ((unsigned int)f2bf(s1) << 16);
            }
        }

    // ---- phase 2: skip -> sk2 = (skip+skip_b)*(1-sig) ----
    #pragma unroll
    for (int mi = 0; mi < 4; mi++)
        #pragma unroll
        for (int ni = 0; ni < 4; ni++) acc[mi][ni] = zero4;
    mfma_loop(xb, skb, IN_DIM, IN_DIM, t0, n0, tid, wm, wn, quad, l16, As, Bs, acc);

    #pragma unroll
    for (int mi = 0; mi < 4; mi++)
        #pragma unroll
        for (int ni = 0; ni < 4; ni++) {
            int n = n0 + wn * 64 + ni * 16 + l16;
            float sb_ = skip_b[n];
            #pragma unroll
            for (int rr = 0; rr < 4; rr++) {
                unsigned int u = sigp[(mi * 4 + ni) * 2 + (rr >> 1)];
                float sig = bf2f((unsigned short)((rr & 1) ? (u >> 16) : (u & 0xffff)));
                float v = (acc[mi][ni][rr] + sb_) * (1.f - sig);
                int t = t0 + wm * 64 + mi * 16 + quad * 4 + rr;
                sk2[(size_t)t * OUT_DIM + n] = f2bf(v);
            }
        }

    // ---- phase 3: mix -> zg = (z+mix_b)*sig ----
    #pragma unroll
    for (int mi = 0; mi < 4; mi++)
        #pragma unroll
        for (int ni = 0; ni < 4; ni++) acc[mi][ni] = zero4;
    mfma_loop(zinb, mixb, KMIX, KMIX, t0, n0, tid, wm, wn, quad, l16, As, Bs, acc);

    #pragma unroll
    for (int mi = 0; mi < 4; mi++)
        #pragma unroll
        for (int ni = 0; ni < 4; ni++) {
            int n = n0 + wn * 64 + ni * 16 + l16;
            float mb_ = mix_b[n];
            #pragma unroll
            for (int rr = 0; rr < 4; rr++) {
                unsigned int u = sigp[(mi * 4 + ni) * 2 + (rr >> 1)];
                float sig = bf2f((unsigned short)((rr & 1) ? (u >> 16) : (u & 0xffff)));
                float v = (acc[mi][ni][rr] + mb_) * sig;
                int t = t0 + wm * 64 + mi * 16 + quad * 4 + rr;
                zg[(size_t)t * OUT_DIM + n] = f2bf(v);
            }
        }
}

// ---------------- G3: LayerNorm + residual (bf16 in, fp32 out) --------------------------------
__global__ __launch_bounds__(256) void g3_ln(const unsigned short* __restrict__ zg,
        const unsigned short* __restrict__ sk2, float* __restrict__ out)
{
    __shared__ float sb[4], qb[4];
    __shared__ float mu_s, rstd_s;
    const int t = blockIdx.x;
    const int tid = threadIdx.x;
    ushort4 zu = *(const ushort4*)&zg [(size_t)t * OUT_DIM + tid * 4];
    ushort4 su = *(const ushort4*)&sk2[(size_t)t * OUT_DIM + tid * 4];
    float z0 = bf2f(zu.x), z1 = bf2f(zu.y), z2 = bf2f(zu.z), z3 = bf2f(zu.w);
    float s0 = bf2f(su.x), s1 = bf2f(su.y), s2 = bf2f(su.z), s3 = bf2f(su.w);
    float s = z0 + z1 + z2 + z3;
    float q = z0*z0 + z1*z1 + z2*z2 + z3*z3;
    #pragma unroll
    for (int off = 32; off > 0; off >>= 1) {
        s += __shfl_down(s, off, 64);
        q += __shfl_down(q, off, 64);
    }
    int wid = tid >> 6;
    if ((tid & 63) == 0) { sb[wid] = s; qb[wid] = q; }
    __syncthreads();
    if (tid == 0) {
        float S = sb[0] + sb[1] + sb[2] + sb[3];
        float Q = qb[0] + qb[1] + qb[2] + qb[3];
        float mu = S * (1.f / 1024.f);
        float var = Q * (1.f / 1024.f) - mu * mu;
        mu_s = mu; rstd_s = rsqrtf(var + 1e-5f);
    }
    __syncthreads();
    float mu = mu_s, rs = rstd_s;
    float4 o;
    o.x = (z0 - mu) * rs + s0;
    o.y = (z1 - mu) * rs + s1;
    o.z = (z2 - mu) * rs + s2;
    o.w = (z3 - mu) * rs + s3;
    *(float4*)&out[(size_t)t * OUT_DIM + tid * 4] = o;
}

// ---------------- G4: final_state copy (planar re/im, guarded) --------------------------------
__global__ void g4_final(const float* __restrict__ fstate, float* __restrict__ out, int out_size)
{
    int i = blockIdx.x * blockDim.x + threadIdx.x;
    if (i >= 2048) return;
    long long base = (long long)T_DIM * OUT_DIM;
    if (base + i < (long long)out_size) out[base + i] = fstate[i];
}

extern "C" void kernel_launch(void* const* d_in, const int* in_sizes, int n_in,
                              void* d_out, int out_size, void* d_ws, size_t ws_size,
                              hipStream_t stream) {
    const float* x        = (const float*)d_in[0];
    const float* state_re = (const float*)d_in[1];
    const float* state_im = (const float*)d_in[2];
    const void*  startp   = d_in[3];
    const float* pre_w    = (const float*)d_in[5];
    const float* pre_b    = (const float*)d_in[6];
    const float* gi_w     = (const float*)d_in[7];
    const float* gi_b     = (const float*)d_in[8];
    const float* go_w     = (const float*)d_in[9];
    const float* go_b     = (const float*)d_in[10];
    const float* skip_w   = (const float*)d_in[11];
    const float* skip_b   = (const float*)d_in[12];
    const float* mix_w    = (const float*)d_in[13];
    const float* mix_b    = (const float*)d_in[14];
    const float* ffa_a    = (const float*)d_in[15];
    const float* ffa_b    = (const float*)d_in[16];

    float* ws = (float*)d_ws;
    float*          gxT    = ws;
    unsigned short* zinTb  = (unsigned short*)(ws + 524288);
    unsigned short* zinb   = (unsigned short*)(ws + 8912896);
    unsigned short* xb     = (unsigned short*)(ws + 17301504);
    unsigned short* gob    = (unsigned short*)(ws + 21495808);
    unsigned short* skb    = (unsigned short*)(ws + 22020096);
    unsigned short* mixb   = (unsigned short*)(ws + 22544384);
    unsigned short* zg     = (unsigned short*)(ws + 23592960);
    unsigned short* sk2    = (unsigned short*)(ws + 27787264);
    float*          fstate = ws + 31981568;
    unsigned char*  mask   = (unsigned char*)(ws + 31983616);
    float* out = (float*)d_out;

    hipLaunchKernelGGL(k0_start, dim3(1),          dim3(1024), 0, stream, startp, mask);
    hipLaunchKernelGGL(c0_conv,  dim3(1536),       dim3(256),  0, stream, x, go_w, skip_w, mix_w, xb, gob, skb, mixb);
    hipLaunchKernelGGL(k1_gate,  dim3(256),        dim3(256),  0, stream, x, pre_w, pre_b, gi_w, gi_b, gxT);
    hipLaunchKernelGGL(k2_scan,  dim3(1024),       dim3(128),  0, stream, gxT, mask, state_re, state_im, ffa_a, ffa_b, zinTb, fstate);
    hipLaunchKernelGGL(t3_tr,    dim3(32, 128),    dim3(256),  0, stream, zinTb, zinb);
    hipLaunchKernelGGL(gA_gemm,  dim3(8, 64),      dim3(256),  0, stream, xb, zinb, gob, skb, mixb, go_b, skip_b, mix_b, zg, sk2);
    hipLaunchKernelGGL(g3_ln,    dim3(8192),       dim3(256),  0, stream, zg, sk2, out);
    hipLaunchKernelGGL(g4_final, dim3(8),          dim3(256),  0, stream, fstate, out, out_size);
}

// Round 5
// 320.253 us; speedup vs baseline: 3.6843x; 1.1511x over previous
//
#include <hip/hip_runtime.h>
#include <math.h>

#define T_DIM 8192
#define IN_DIM 1024
#define TRACE 64
#define CTX 16
#define OUT_DIM 1024
#define KMIX 2048

typedef __attribute__((ext_vector_type(8))) short bf16x8;
typedef __attribute__((ext_vector_type(4))) float f32x4;

__device__ __forceinline__ unsigned short f2bf(float f) {
    unsigned int u = __float_as_uint(f);
    u = (u + 0x7FFFu + ((u >> 16) & 1u)) >> 16;
    return (unsigned short)u;
}
__device__ __forceinline__ float bf2f(unsigned short b) {
    return __uint_as_float(((unsigned int)b) << 16);
}

__device__ __forceinline__ void gl2lds16(const void* g, void* l) {
    __builtin_amdgcn_global_load_lds(
        (const __attribute__((address_space(1))) unsigned int*)g,
        (__attribute__((address_space(3))) unsigned int*)l,
        16, 0, 0);
}

// ---------------- ws layout (float offsets) ----------------
// gxT   fp32 [64][8192]      @ 0         (524288 f)
// zinTb bf16 [2048][8192]    @ 524288    (8388608 f)
// zinb  bf16 [8192][2048]    @ 8912896   (8388608 f)
// xb    bf16 [8192][1024]    @ 17301504  (4194304 f)
// gob   bf16 [1024][1024]    @ 21495808  (524288 f)
// skb   bf16 [1024][1024]    @ 22020096  (524288 f)
// mixb  bf16 [1024][2048]    @ 22544384  (1048576 f)
// zg    bf16 [8192][1024]    @ 23592960  (4194304 f)   [pwb/gwb borrow this space pre-gA]
// sk2   bf16 [8192][1024]    @ 27787264  (4194304 f)
// fstate fp32 [2048]         @ 31981568
// mask  u8   [8192]          @ 31983616

// ---------------- K0: normalize `start` to uint8 mask -----------------------------------------
__global__ void k0_start(const void* __restrict__ startp, unsigned char* __restrict__ mask)
{
    __shared__ int nonbool;
    int tid = threadIdx.x;
    if (tid == 0) nonbool = 0;
    __syncthreads();
    const unsigned int* w = (const unsigned int*)startp;
    unsigned int a = w[tid];
    unsigned int b = w[tid + 1024];
    if (a > 1u || b > 1u) nonbool = 1;
    __syncthreads();
    if (nonbool) {
        const unsigned char* s8 = (const unsigned char*)startp;
        for (int i = tid; i < T_DIM; i += 1024) mask[i] = (unsigned char)(s8[i] != 0);
    } else {
        const int* s32 = (const int*)startp;
        for (int i = tid; i < T_DIM; i += 1024) mask[i] = (unsigned char)(s32[i] != 0);
    }
}

// ---------------- C0: fp32 -> bf16 conversions (x, go_w, skip_w, mix_w, pre_w, gi_w) ----------
__global__ __launch_bounds__(256) void c0_conv(const float* __restrict__ x,
        const float* __restrict__ gw, const float* __restrict__ sw, const float* __restrict__ mw,
        const float* __restrict__ pw, const float* __restrict__ giw,
        unsigned short* __restrict__ xb, unsigned short* __restrict__ gob,
        unsigned short* __restrict__ skb, unsigned short* __restrict__ mixb,
        unsigned short* __restrict__ pwb, unsigned short* __restrict__ gwb)
{
    const size_t QX = 2097152, QG = 262144, QS = 262144, QM = 524288, QP = 16384, QI = 16384;
    const size_t total = QX + QG + QS + QM + QP + QI;
    for (size_t q = (size_t)blockIdx.x * blockDim.x + threadIdx.x; q < total;
         q += (size_t)gridDim.x * blockDim.x) {
        const float* src; unsigned short* dst; size_t i;
        if (q < QX)                  { src = x;   dst = xb;   i = q; }
        else if (q < QX+QG)          { src = gw;  dst = gob;  i = q - QX; }
        else if (q < QX+QG+QS)       { src = sw;  dst = skb;  i = q - QX - QG; }
        else if (q < QX+QG+QS+QM)    { src = mw;  dst = mixb; i = q - QX - QG - QS; }
        else if (q < QX+QG+QS+QM+QP) { src = pw;  dst = pwb;  i = q - QX - QG - QS - QM; }
        else                         { src = giw; dst = gwb;  i = q - QX - QG - QS - QM - QP; }
        float4 v = *(const float4*)(src + i * 4);
        ushort4 o;
        o.x = f2bf(v.x); o.y = f2bf(v.y); o.z = f2bf(v.z); o.w = f2bf(v.w);
        *(ushort4*)(dst + i * 4) = o;
    }
}

// ---------------- K1: MFMA gated_x. B = [pre_w(64); gi_w(64)] stacked. 64 blocks --------------
__global__ __launch_bounds__(256) void k1_mfma(const unsigned short* __restrict__ xb,
        const unsigned short* __restrict__ pwb, const unsigned short* __restrict__ gwb,
        const float* __restrict__ pre_b, const float* __restrict__ gi_b,
        float* __restrict__ gxT)
{
    __shared__ __align__(16) unsigned short As[4096];   // 128 t x 32 k
    __shared__ __align__(16) unsigned short Bs[4096];   // 128 n x 32 k (0-63 pre, 64-127 gi)
    __shared__ float sgE[64][133];                      // sigmoid(gi) [m][t_local]

    const int tid = threadIdx.x;
    const int t0 = blockIdx.x * 128;
    const int lane = tid & 63, w = tid >> 6;
    const int wm = w >> 1, wn = w & 1;
    const int quad = lane >> 4, l16 = lane & 15;
    const int r = tid >> 2, c = (tid & 3) * 8;

    const unsigned short* gA0 = xb  + (size_t)(t0 + r)      * IN_DIM + c;
    const unsigned short* gA1 = xb  + (size_t)(t0 + 64 + r) * IN_DIM + c;
    const unsigned short* gB0 = pwb + (size_t)r * IN_DIM + c;
    const unsigned short* gB1 = gwb + (size_t)r * IN_DIM + c;
    unsigned short* lA0 = As + tid * 8;
    unsigned short* lA1 = As + 2048 + tid * 8;
    unsigned short* lB0 = Bs + tid * 8;
    unsigned short* lB1 = Bs + 2048 + tid * 8;

    f32x4 acc[4][4];
    const f32x4 zero4 = {0.f, 0.f, 0.f, 0.f};
    #pragma unroll
    for (int mi = 0; mi < 4; mi++)
        #pragma unroll
        for (int ni = 0; ni < 4; ni++) acc[mi][ni] = zero4;

    for (int k0 = 0; k0 < IN_DIM; k0 += 32) {
        __syncthreads();
        gl2lds16(gA0 + k0, lA0);
        gl2lds16(gA1 + k0, lA1);
        gl2lds16(gB0 + k0, lB0);
        gl2lds16(gB1 + k0, lB1);
        asm volatile("s_waitcnt vmcnt(0)" ::: "memory");
        __syncthreads();
        bf16x8 af[4], bf[4];
        #pragma unroll
        for (int mi = 0; mi < 4; mi++)
            af[mi] = *(const bf16x8*)&As[(wm * 64 + mi * 16 + l16) * 32 + quad * 8];
        #pragma unroll
        for (int ni = 0; ni < 4; ni++)
            bf[ni] = *(const bf16x8*)&Bs[(wn * 64 + ni * 16 + l16) * 32 + quad * 8];
        #pragma unroll
        for (int mi = 0; mi < 4; mi++)
            #pragma unroll
            for (int ni = 0; ni < 4; ni++)
                acc[mi][ni] = __builtin_amdgcn_mfma_f32_16x16x32_bf16(af[mi], bf[ni], acc[mi][ni], 0, 0, 0);
    }

    // wn=1 waves hold gi (n in [64,128)): sigmoid -> LDS
    if (wn == 1) {
        #pragma unroll
        for (int mi = 0; mi < 4; mi++)
            #pragma unroll
            for (int ni = 0; ni < 4; ni++) {
                int mg = ni * 16 + l16;
                float gb = gi_b[mg];
                #pragma unroll
                for (int rr = 0; rr < 4; rr++) {
                    int tl = wm * 64 + mi * 16 + quad * 4 + rr;
                    sgE[mg][tl] = 1.f / (1.f + expf(-(acc[mi][ni][rr] + gb)));
                }
            }
    }
    __syncthreads();
    if (wn == 0) {
        #pragma unroll
        for (int mi = 0; mi < 4; mi++)
            #pragma unroll
            for (int ni = 0; ni < 4; ni++) {
                int mp = ni * 16 + l16;
                float pb = pre_b[mp];
                #pragma unroll
                for (int rr = 0; rr < 4; rr++) {
                    int tl = wm * 64 + mi * 16 + quad * 4 + rr;
                    gxT[(size_t)mp * T_DIM + t0 + tl] = (acc[mi][ni][rr] + pb) * sgE[mp][tl];
                }
            }
    }
}

// ---------------- K2: resettable complex scan -> zinTb (bf16) + fstate (fp32) ------------------
__global__ __launch_bounds__(128) void k2_scan(const float* __restrict__ gxT,
        const unsigned char* __restrict__ mask8,
        const float* __restrict__ state_re, const float* __restrict__ state_im,
        const float* __restrict__ ffa_a, const float* __restrict__ ffa_b,
        unsigned short* __restrict__ zinTb, float* __restrict__ fstate)
{
    const int m = blockIdx.x >> 4;
    const int c = blockIdx.x & 15;
    const int j = threadIdx.x;
    __shared__ float Br[128], Bi[128], Er[128], Ei[128];
    __shared__ unsigned char Rf[128];

    const float am = -fabsf(ffa_a[m]);
    const float bc = ffa_b[c];
    const float er = expf(am);
    const float gr = er * cosf(bc);
    const float gi = er * sinf(bc);

    const float* gx = gxT + (size_t)m * T_DIM;
    const int t0 = j * 64;

    unsigned long long rmask = 0ull;
    float sre = 0.f, sim = 0.f;
    bool r = false;
    #pragma unroll 8
    for (int i = 0; i < 64; i++) {
        int t = t0 + i;
        if (mask8[t]) { rmask |= 1ull << i; sre = 0.f; sim = 0.f; r = true; }
        else { float tr_ = sre * gr - sim * gi; sim = sre * gi + sim * gr; sre = tr_; }
        sre += gx[t];
    }
    Br[j] = sre; Bi[j] = sim; Rf[j] = r ? 1 : 0;
    __syncthreads();
    if (j == 0) {
        float e64  = expf(64.f * am);
        float g64r = e64 * cosf(64.f * bc);
        float g64i = e64 * sinf(64.f * bc);
        float pr = state_re[m * CTX + c], pi = state_im[m * CTX + c];
        for (int q = 0; q < 128; q++) {
            Er[q] = pr; Ei[q] = pi;
            if (Rf[q]) { pr = Br[q]; pi = Bi[q]; }
            else {
                float nr = pr * g64r - pi * g64i + Br[q];
                pi       = pr * g64i + pi * g64r + Bi[q];
                pr = nr;
            }
        }
    }
    __syncthreads();
    sre = Er[j]; sim = Ei[j];
    unsigned int ore[32], oim[32];
    #pragma unroll
    for (int i = 0; i < 64; i++) {
        int t = t0 + i;
        if (rmask & (1ull << i)) { sre = 0.f; sim = 0.f; }
        else { float tr_ = sre * gr - sim * gi; sim = sre * gi + sim * gr; sre = tr_; }
        sre += gx[t];
        unsigned short hr = f2bf(sre), hi_ = f2bf(sim);
        if (i & 1) { ore[i >> 1] |= ((unsigned int)hr) << 16; oim[i >> 1] |= ((unsigned int)hi_) << 16; }
        else       { ore[i >> 1]  = hr;                        oim[i >> 1]  = hi_; }
    }
    unsigned short* zreb = zinTb + (size_t)(m * 32 + c)      * T_DIM;
    unsigned short* zimb = zinTb + (size_t)(m * 32 + 16 + c) * T_DIM;
    uint4* pre4 = (uint4*)(zreb + t0);
    uint4* pim4 = (uint4*)(zimb + t0);
    #pragma unroll
    for (int q = 0; q < 8; q++) pre4[q] = *(uint4*)&ore[q * 4];
    #pragma unroll
    for (int q = 0; q < 8; q++) pim4[q] = *(uint4*)&oim[q * 4];

    if (j == 127) {
        int p = m * CTX + c;
        fstate[p]        = sre;
        fstate[1024 + p] = sim;
    }
}

// ---------------- T3: transpose zinTb[k][t] -> zinb[t][k], 64x64 tiles -------------------------
__global__ __launch_bounds__(256) void t3_tr(const unsigned short* __restrict__ zinTb,
                                             unsigned short* __restrict__ zinb)
{
    __shared__ unsigned short S[64][72];
    const int k0 = blockIdx.x * 64, t0 = blockIdx.y * 64;
    const int tid = threadIdx.x;
    {
        int kr = tid >> 3, tc = (tid & 7) * 8;
        #pragma unroll
        for (int p = 0; p < 2; p++) {
            int k = kr + p * 32;
            ushort4 a = *(const ushort4*)&zinTb[(size_t)(k0 + k) * T_DIM + t0 + tc];
            ushort4 b = *(const ushort4*)&zinTb[(size_t)(k0 + k) * T_DIM + t0 + tc + 4];
            *(ushort4*)&S[k][tc]     = a;
            *(ushort4*)&S[k][tc + 4] = b;
        }
    }
    __syncthreads();
    {
        int tr = tid >> 3, kc = (tid & 7) * 8;
        #pragma unroll
        for (int p = 0; p < 2; p++) {
            int t = tr + p * 32;
            ushort4 o1, o2;
            o1.x = S[kc+0][t]; o1.y = S[kc+1][t]; o1.z = S[kc+2][t]; o1.w = S[kc+3][t];
            o2.x = S[kc+4][t]; o2.y = S[kc+5][t]; o2.z = S[kc+6][t]; o2.w = S[kc+7][t];
            *(ushort4*)&zinb[(size_t)(t0 + t) * KMIX + k0 + kc]     = o1;
            *(ushort4*)&zinb[(size_t)(t0 + t) * KMIX + k0 + kc + 4] = o2;
        }
    }
}

// ---------------- GA: fused [go+skip] dual-B phase, then mix phase. XCD-swizzled ---------------
__global__ __launch_bounds__(256, 2) void gA_gemm(
        const unsigned short* __restrict__ xb,   const unsigned short* __restrict__ zinb,
        const unsigned short* __restrict__ gob,  const unsigned short* __restrict__ skb,
        const unsigned short* __restrict__ mixb,
        const float* __restrict__ go_b, const float* __restrict__ skip_b, const float* __restrict__ mix_b,
        unsigned short* __restrict__ zg, unsigned short* __restrict__ sk2)
{
    __shared__ __align__(16) unsigned short As[4096];
    __shared__ __align__(16) unsigned short Bs[4096];
    __shared__ __align__(16) unsigned short Cs[4096];
    const int tid = threadIdx.x;
    // XCD-aware swizzle: blocks sharing a t-band (A tile) stay on one XCD.
    const int b = blockIdx.x;               // 512 blocks
    const int xcd = b & 7, q = b >> 3;      // 64 per XCD
    const int t0 = (xcd * 8 + (q >> 3)) * 128;
    const int n0 = (q & 7) * 128;

    const int lane = tid & 63, w = tid >> 6;
    const int wm = w >> 1, wn = w & 1;
    const int quad = lane >> 4, l16 = lane & 15;
    const int r = tid >> 2, c = (tid & 3) * 8;

    unsigned short* lA0 = As + tid * 8;
    unsigned short* lA1 = As + 2048 + tid * 8;
    unsigned short* lB0 = Bs + tid * 8;
    unsigned short* lB1 = Bs + 2048 + tid * 8;
    unsigned short* lC0 = Cs + tid * 8;
    unsigned short* lC1 = Cs + 2048 + tid * 8;

    f32x4 accg[4][4], acck[4][4];
    const f32x4 zero4 = {0.f, 0.f, 0.f, 0.f};
    #pragma unroll
    for (int mi = 0; mi < 4; mi++)
        #pragma unroll
        for (int ni = 0; ni < 4; ni++) { accg[mi][ni] = zero4; acck[mi][ni] = zero4; }

    // ---- fused phase: go + skip (shared A = xb) ----
    {
        const unsigned short* gA0 = xb  + (size_t)(t0 + r)      * IN_DIM + c;
        const unsigned short* gA1 = xb  + (size_t)(t0 + 64 + r) * IN_DIM + c;
        const unsigned short* gB0 = gob + (size_t)(n0 + r)      * IN_DIM + c;
        const unsigned short* gB1 = gob + (size_t)(n0 + 64 + r) * IN_DIM + c;
        const unsigned short* gC0 = skb + (size_t)(n0 + r)      * IN_DIM + c;
        const unsigned short* gC1 = skb + (size_t)(n0 + 64 + r) * IN_DIM + c;
        for (int k0 = 0; k0 < IN_DIM; k0 += 32) {
            __syncthreads();
            gl2lds16(gA0 + k0, lA0);
            gl2lds16(gA1 + k0, lA1);
            gl2lds16(gB0 + k0, lB0);
            gl2lds16(gB1 + k0, lB1);
            gl2lds16(gC0 + k0, lC0);
            gl2lds16(gC1 + k0, lC1);
            asm volatile("s_waitcnt vmcnt(0)" ::: "memory");
            __syncthreads();
            bf16x8 af[4], bg[4], bk[4];
            #pragma unroll
            for (int mi = 0; mi < 4; mi++)
                af[mi] = *(const bf16x8*)&As[(wm * 64 + mi * 16 + l16) * 32 + quad * 8];
            #pragma unroll
            for (int ni = 0; ni < 4; ni++) {
                bg[ni] = *(const bf16x8*)&Bs[(wn * 64 + ni * 16 + l16) * 32 + quad * 8];
                bk[ni] = *(const bf16x8*)&Cs[(wn * 64 + ni * 16 + l16) * 32 + quad * 8];
            }
            #pragma unroll
            for (int mi = 0; mi < 4; mi++)
                #pragma unroll
                for (int ni = 0; ni < 4; ni++) {
                    accg[mi][ni] = __builtin_amdgcn_mfma_f32_16x16x32_bf16(af[mi], bg[ni], accg[mi][ni], 0, 0, 0);
                    acck[mi][ni] = __builtin_amdgcn_mfma_f32_16x16x32_bf16(af[mi], bk[ni], acck[mi][ni], 0, 0, 0);
                }
        }
    }

    // sigmoid (packed bf16 pairs) + sk2 write
    unsigned int sigp[32];
    #pragma unroll
    for (int mi = 0; mi < 4; mi++)
        #pragma unroll
        for (int ni = 0; ni < 4; ni++) {
            int n = n0 + wn * 64 + ni * 16 + l16;
            float gb = go_b[n];
            float sb_ = skip_b[n];
            #pragma unroll
            for (int r2 = 0; r2 < 2; r2++) {
                float s0 = 1.f / (1.f + expf(-(accg[mi][ni][r2 * 2]     + gb)));
                float s1 = 1.f / (1.f + expf(-(accg[mi][ni][r2 * 2 + 1] + gb)));
                sigp[(mi * 4 + ni) * 2 + r2] =
                    (unsigned int)f2bf(s0) | ((unsigned int)f2bf(s1) << 16);
                int t = t0 + wm * 64 + mi * 16 + quad * 4 + r2 * 2;
                sk2[(size_t)t * OUT_DIM + n]       = f2bf((acck[mi][ni][r2*2]   + sb_) * (1.f - s0));
                sk2[(size_t)(t+1) * OUT_DIM + n]   = f2bf((acck[mi][ni][r2*2+1] + sb_) * (1.f - s1));
            }
        }

    // ---- mix phase (K=2048) ----
    #pragma unroll
    for (int mi = 0; mi < 4; mi++)
        #pragma unroll
        for (int ni = 0; ni < 4; ni++) accg[mi][ni] = zero4;
    {
        const unsigned short* gA0 = zinb + (size_t)(t0 + r)      * KMIX + c;
        const unsigned short* gA1 = zinb + (size_t)(t0 + 64 + r) * KMIX + c;
        const unsigned short* gB0 = mixb + (size_t)(n0 + r)      * KMIX + c;
        const unsigned short* gB1 = mixb + (size_t)(n0 + 64 + r) * KMIX + c;
        for (int k0 = 0; k0 < KMIX; k0 += 32) {
            __syncthreads();
            gl2lds16(gA0 + k0, lA0);
            gl2lds16(gA1 + k0, lA1);
            gl2lds16(gB0 + k0, lB0);
            gl2lds16(gB1 + k0, lB1);
            asm volatile("s_waitcnt vmcnt(0)" ::: "memory");
            __syncthreads();
            bf16x8 af[4], bf[4];
            #pragma unroll
            for (int mi = 0; mi < 4; mi++)
                af[mi] = *(const bf16x8*)&As[(wm * 64 + mi * 16 + l16) * 32 + quad * 8];
            #pragma unroll
            for (int ni = 0; ni < 4; ni++)
                bf[ni] = *(const bf16x8*)&Bs[(wn * 64 + ni * 16 + l16) * 32 + quad * 8];
            #pragma unroll
            for (int mi = 0; mi < 4; mi++)
                #pragma unroll
                for (int ni = 0; ni < 4; ni++)
                    accg[mi][ni] = __builtin_amdgcn_mfma_f32_16x16x32_bf16(af[mi], bf[ni], accg[mi][ni], 0, 0, 0);
        }
    }

    #pragma unroll
    for (int mi = 0; mi < 4; mi++)
        #pragma unroll
        for (int ni = 0; ni < 4; ni++) {
            int n = n0 + wn * 64 + ni * 16 + l16;
            float mb_ = mix_b[n];
            #pragma unroll
            for (int rr = 0; rr < 4; rr++) {
                unsigned int u = sigp[(mi * 4 + ni) * 2 + (rr >> 1)];
                float sig = bf2f((unsigned short)((rr & 1) ? (u >> 16) : (u & 0xffff)));
                float v = (accg[mi][ni][rr] + mb_) * sig;
                int t = t0 + wm * 64 + mi * 16 + quad * 4 + rr;
                zg[(size_t)t * OUT_DIM + n] = f2bf(v);
            }
        }
}

// ---------------- G3: LayerNorm + residual (bf16 in, fp32 out) --------------------------------
__global__ __launch_bounds__(256) void g3_ln(const unsigned short* __restrict__ zg,
        const unsigned short* __restrict__ sk2, float* __restrict__ out)
{
    __shared__ float sb[4], qb[4];
    __shared__ float mu_s, rstd_s;
    const int t = blockIdx.x;
    const int tid = threadIdx.x;
    ushort4 zu = *(const ushort4*)&zg [(size_t)t * OUT_DIM + tid * 4];
    ushort4 su = *(const ushort4*)&sk2[(size_t)t * OUT_DIM + tid * 4];
    float z0 = bf2f(zu.x), z1 = bf2f(zu.y), z2 = bf2f(zu.z), z3 = bf2f(zu.w);
    float s0 = bf2f(su.x), s1 = bf2f(su.y), s2 = bf2f(su.z), s3 = bf2f(su.w);
    float s = z0 + z1 + z2 + z3;
    float q = z0*z0 + z1*z1 + z2*z2 + z3*z3;
    #pragma unroll
    for (int off = 32; off > 0; off >>= 1) {
        s += __shfl_down(s, off, 64);
        q += __shfl_down(q, off, 64);
    }
    int wid = tid >> 6;
    if ((tid & 63) == 0) { sb[wid] = s; qb[wid] = q; }
    __syncthreads();
    if (tid == 0) {
        float S = sb[0] + sb[1] + sb[2] + sb[3];
        float Q = qb[0] + qb[1] + qb[2] + qb[3];
        float mu = S * (1.f / 1024.f);
        float var = Q * (1.f / 1024.f) - mu * mu;
        mu_s = mu; rstd_s = rsqrtf(var + 1e-5f);
    }
    __syncthreads();
    float mu = mu_s, rs = rstd_s;
    float4 o;
    o.x = (z0 - mu) * rs + s0;
    o.y = (z1 - mu) * rs + s1;
    o.z = (z2 - mu) * rs + s2;
    o.w = (z3 - mu) * rs + s3;
    *(float4*)&out[(size_t)t * OUT_DIM + tid * 4] = o;
}

// ---------------- G4: final_state copy (planar re/im, guarded) --------------------------------
__global__ void g4_final(const float* __restrict__ fstate, float* __restrict__ out, int out_size)
{
    int i = blockIdx.x * blockDim.x + threadIdx.x;
    if (i >= 2048) return;
    long long base = (long long)T_DIM * OUT_DIM;
    if (base + i < (long long)out_size) out[base + i] = fstate[i];
}

extern "C" void kernel_launch(void* const* d_in, const int* in_sizes, int n_in,
                              void* d_out, int out_size, void* d_ws, size_t ws_size,
                              hipStream_t stream) {
    const float* x        = (const float*)d_in[0];
    const float* state_re = (const float*)d_in[1];
    const float* state_im = (const float*)d_in[2];
    const void*  startp   = d_in[3];
    const float* pre_w    = (const float*)d_in[5];
    const float* pre_b    = (const float*)d_in[6];
    const float* gi_w     = (const float*)d_in[7];
    const float* gi_b     = (const float*)d_in[8];
    const float* go_w     = (const float*)d_in[9];
    const float* go_b     = (const float*)d_in[10];
    const float* skip_w   = (const float*)d_in[11];
    const float* skip_b   = (const float*)d_in[12];
    const float* mix_w    = (const float*)d_in[13];
    const float* mix_b    = (const float*)d_in[14];
    const float* ffa_a    = (const float*)d_in[15];
    const float* ffa_b    = (const float*)d_in[16];

    float* ws = (float*)d_ws;
    float*          gxT    = ws;
    unsigned short* zinTb  = (unsigned short*)(ws + 524288);
    unsigned short* zinb   = (unsigned short*)(ws + 8912896);
    unsigned short* xb     = (unsigned short*)(ws + 17301504);
    unsigned short* gob    = (unsigned short*)(ws + 21495808);
    unsigned short* skb    = (unsigned short*)(ws + 22020096);
    unsigned short* mixb   = (unsigned short*)(ws + 22544384);
    unsigned short* zg     = (unsigned short*)(ws + 23592960);
    unsigned short* sk2    = (unsigned short*)(ws + 27787264);
    float*          fstate = ws + 31981568;
    unsigned char*  mask   = (unsigned char*)(ws + 31983616);
    // pwb/gwb borrow the zg region (overwritten later by gA_gemm, used only by k1_mfma before it)
    unsigned short* pwb    = zg;            // 65536 ushorts
    unsigned short* gwb    = zg + 65536;    // 65536 ushorts
    float* out = (float*)d_out;

    hipLaunchKernelGGL(k0_start, dim3(1),       dim3(1024), 0, stream, startp, mask);
    hipLaunchKernelGGL(c0_conv,  dim3(1536),    dim3(256),  0, stream, x, go_w, skip_w, mix_w, pre_w, gi_w,
                                                             xb, gob, skb, mixb, pwb, gwb);
    hipLaunchKernelGGL(k1_mfma,  dim3(64),      dim3(256),  0, stream, xb, pwb, gwb, pre_b, gi_b, gxT);
    hipLaunchKernelGGL(k2_scan,  dim3(1024),    dim3(128),  0, stream, gxT, mask, state_re, state_im, ffa_a, ffa_b, zinTb, fstate);
    hipLaunchKernelGGL(t3_tr,    dim3(32, 128), dim3(256),  0, stream, zinTb, zinb);
    hipLaunchKernelGGL(gA_gemm,  dim3(512),     dim3(256),  0, stream, xb, zinb, gob, skb, mixb, go_b, skip_b, mix_b, zg, sk2);
    hipLaunchKernelGGL(g3_ln,    dim3(8192),    dim3(256),  0, stream, zg, sk2, out);
    hipLaunchKernelGGL(g4_final, dim3(8),       dim3(256),  0, stream, fstate, out, out_size);
}

// Round 6
// 305.022 us; speedup vs baseline: 3.8682x; 1.0499x over previous
//
#include <hip/hip_runtime.h>
#include <math.h>

#define T_DIM 8192
#define IN_DIM 1024
#define TRACE 64
#define CTX 16
#define OUT_DIM 1024
#define KMIX 2048

typedef __attribute__((ext_vector_type(8))) short bf16x8;
typedef __attribute__((ext_vector_type(4))) float f32x4;
typedef __attribute__((ext_vector_type(16))) float f32x16;

__device__ __forceinline__ unsigned short f2bf(float f) {
    unsigned int u = __float_as_uint(f);
    u = (u + 0x7FFFu + ((u >> 16) & 1u)) >> 16;
    return (unsigned short)u;
}
__device__ __forceinline__ float bf2f(unsigned short b) {
    return __uint_as_float(((unsigned int)b) << 16);
}

__device__ __forceinline__ void gl2lds16(const void* g, void* l) {
    __builtin_amdgcn_global_load_lds(
        (const __attribute__((address_space(1))) unsigned int*)g,
        (__attribute__((address_space(3))) unsigned int*)l,
        16, 0, 0);
}

// ---------------- ws layout (float offsets) ----------------
// gxT   fp32 [64][8192]      @ 0         (524288 f)
// zinTb bf16 [2048][8192]    @ 524288    (8388608 f)
// zinb  bf16 [8192][2048]    @ 8912896   (8388608 f)
// xb    bf16 [8192][1024]    @ 17301504  (4194304 f)
// gob   bf16 [1024][1024]    @ 21495808  (524288 f)
// skb   bf16 [1024][1024]    @ 22020096  (524288 f)
// mixb  bf16 [1024][2048]    @ 22544384  (1048576 f)
// zg    bf16 [8192][1024]    @ 23592960  (4194304 f)   [pwb/gwb borrow pre-gA]
// sk2   bf16 [8192][1024]    @ 27787264  (4194304 f)
// fstate fp32 [2048]         @ 31981568
// mask  u8   [8192]          @ 31983616

// ---------------- K0: normalize `start` to uint8 mask -----------------------------------------
__global__ void k0_start(const void* __restrict__ startp, unsigned char* __restrict__ mask)
{
    __shared__ int nonbool;
    int tid = threadIdx.x;
    if (tid == 0) nonbool = 0;
    __syncthreads();
    const unsigned int* w = (const unsigned int*)startp;
    unsigned int a = w[tid];
    unsigned int b = w[tid + 1024];
    if (a > 1u || b > 1u) nonbool = 1;
    __syncthreads();
    if (nonbool) {
        const unsigned char* s8 = (const unsigned char*)startp;
        for (int i = tid; i < T_DIM; i += 1024) mask[i] = (unsigned char)(s8[i] != 0);
    } else {
        const int* s32 = (const int*)startp;
        for (int i = tid; i < T_DIM; i += 1024) mask[i] = (unsigned char)(s32[i] != 0);
    }
}

// ---------------- C0: fp32 -> bf16 conversions -------------------------------------------------
__global__ __launch_bounds__(256) void c0_conv(const float* __restrict__ x,
        const float* __restrict__ gw, const float* __restrict__ sw, const float* __restrict__ mw,
        const float* __restrict__ pw, const float* __restrict__ giw,
        unsigned short* __restrict__ xb, unsigned short* __restrict__ gob,
        unsigned short* __restrict__ skb, unsigned short* __restrict__ mixb,
        unsigned short* __restrict__ pwb, unsigned short* __restrict__ gwb)
{
    const size_t QX = 2097152, QG = 262144, QS = 262144, QM = 524288, QP = 16384, QI = 16384;
    const size_t total = QX + QG + QS + QM + QP + QI;
    for (size_t q = (size_t)blockIdx.x * blockDim.x + threadIdx.x; q < total;
         q += (size_t)gridDim.x * blockDim.x) {
        const float* src; unsigned short* dst; size_t i;
        if (q < QX)                  { src = x;   dst = xb;   i = q; }
        else if (q < QX+QG)          { src = gw;  dst = gob;  i = q - QX; }
        else if (q < QX+QG+QS)       { src = sw;  dst = skb;  i = q - QX - QG; }
        else if (q < QX+QG+QS+QM)    { src = mw;  dst = mixb; i = q - QX - QG - QS; }
        else if (q < QX+QG+QS+QM+QP) { src = pw;  dst = pwb;  i = q - QX - QG - QS - QM; }
        else                         { src = giw; dst = gwb;  i = q - QX - QG - QS - QM - QP; }
        float4 v = *(const float4*)(src + i * 4);
        ushort4 o;
        o.x = f2bf(v.x); o.y = f2bf(v.y); o.z = f2bf(v.z); o.w = f2bf(v.w);
        *(ushort4*)(dst + i * 4) = o;
    }
}

// ---------------- K1: MFMA gated_x, 256 blocks of 32t x 128m -----------------------------------
// B rows: [0..63] = pre_w, [64..127] = gi_w. Waves 0-1 -> pre, waves 2-3 -> gi.
__global__ __launch_bounds__(256) void k1_mfma(const unsigned short* __restrict__ xb,
        const unsigned short* __restrict__ pwb, const unsigned short* __restrict__ gwb,
        const float* __restrict__ pre_b, const float* __restrict__ gi_b,
        float* __restrict__ gxT)
{
    __shared__ __align__(16) unsigned short As[1024];   // 32 t x 32 k
    __shared__ __align__(16) unsigned short Bs[4096];   // 128 n x 32 k
    __shared__ float sgE[64][33];                       // sigmoid(gi) [m][t_local]

    const int tid = threadIdx.x;
    const int t0 = blockIdx.x * 32;
    const int lane = tid & 63, w = tid >> 6;
    const int quad = lane >> 4, l16 = lane & 15;
    const int r = tid >> 2, c8 = (tid & 3) * 8;

    f32x4 acc[2][2];
    const f32x4 zero4 = {0.f, 0.f, 0.f, 0.f};
    #pragma unroll
    for (int mi = 0; mi < 2; mi++)
        #pragma unroll
        for (int ni = 0; ni < 2; ni++) acc[mi][ni] = zero4;

    for (int k0 = 0; k0 < IN_DIM; k0 += 32) {
        __syncthreads();
        if (tid < 128)
            gl2lds16(xb + (size_t)(t0 + (tid >> 2)) * IN_DIM + k0 + (tid & 3) * 8, As + tid * 8);
        gl2lds16(pwb + (size_t)r * IN_DIM + k0 + c8, Bs + tid * 8);
        gl2lds16(gwb + (size_t)r * IN_DIM + k0 + c8, Bs + 2048 + tid * 8);
        asm volatile("s_waitcnt vmcnt(0)" ::: "memory");
        __syncthreads();
        bf16x8 af[2], bf[2];
        #pragma unroll
        for (int mi = 0; mi < 2; mi++)
            af[mi] = *(const bf16x8*)&As[(mi * 16 + l16) * 32 + quad * 8];
        #pragma unroll
        for (int ni = 0; ni < 2; ni++)
            bf[ni] = *(const bf16x8*)&Bs[(w * 32 + ni * 16 + l16) * 32 + quad * 8];
        #pragma unroll
        for (int mi = 0; mi < 2; mi++)
            #pragma unroll
            for (int ni = 0; ni < 2; ni++)
                acc[mi][ni] = __builtin_amdgcn_mfma_f32_16x16x32_bf16(af[mi], bf[ni], acc[mi][ni], 0, 0, 0);
    }

    if (w >= 2) {   // gi waves
        #pragma unroll
        for (int mi = 0; mi < 2; mi++)
            #pragma unroll
            for (int ni = 0; ni < 2; ni++) {
                int mg = (w - 2) * 32 + ni * 16 + l16;
                float gb = gi_b[mg];
                #pragma unroll
                for (int rr = 0; rr < 4; rr++) {
                    int tl = mi * 16 + quad * 4 + rr;
                    sgE[mg][tl] = 1.f / (1.f + expf(-(acc[mi][ni][rr] + gb)));
                }
            }
    }
    __syncthreads();
    if (w < 2) {    // pre waves
        #pragma unroll
        for (int mi = 0; mi < 2; mi++)
            #pragma unroll
            for (int ni = 0; ni < 2; ni++) {
                int mp = w * 32 + ni * 16 + l16;
                float pb = pre_b[mp];
                float4 o;
                float* po = &o.x;
                #pragma unroll
                for (int rr = 0; rr < 4; rr++) {
                    int tl = mi * 16 + quad * 4 + rr;
                    po[rr] = (acc[mi][ni][rr] + pb) * sgE[mp][tl];
                }
                *(float4*)&gxT[(size_t)mp * T_DIM + t0 + mi * 16 + quad * 4] = o;
            }
    }
}

// ---------------- K2: resettable complex scan; LDS-staged coalesced output --------------------
__global__ __launch_bounds__(128) void k2_scan(const float* __restrict__ gxT,
        const unsigned char* __restrict__ mask8,
        const float* __restrict__ state_re, const float* __restrict__ state_im,
        const float* __restrict__ ffa_a, const float* __restrict__ ffa_b,
        unsigned short* __restrict__ zinTb, float* __restrict__ fstate)
{
    const int m = blockIdx.x >> 4;
    const int c = blockIdx.x & 15;
    const int j = threadIdx.x;
    __shared__ float Br[128], Bi[128], Er[128], Ei[128];
    __shared__ unsigned char Rf[128];
    __shared__ unsigned int SB[128 * 33];   // padded: bank = (j+q)%32, 2-way (free)

    const float am = -fabsf(ffa_a[m]);
    const float bc = ffa_b[c];
    const float er = expf(am);
    const float gr = er * cosf(bc);
    const float gi = er * sinf(bc);

    const float* gx = gxT + (size_t)m * T_DIM;
    const int t0 = j * 64;

    unsigned long long rmask = 0ull;
    float sre = 0.f, sim = 0.f;
    bool r = false;
    #pragma unroll 8
    for (int i = 0; i < 64; i++) {
        int t = t0 + i;
        if (mask8[t]) { rmask |= 1ull << i; sre = 0.f; sim = 0.f; r = true; }
        else { float tr_ = sre * gr - sim * gi; sim = sre * gi + sim * gr; sre = tr_; }
        sre += gx[t];
    }
    Br[j] = sre; Bi[j] = sim; Rf[j] = r ? 1 : 0;
    __syncthreads();
    if (j == 0) {
        float e64  = expf(64.f * am);
        float g64r = e64 * cosf(64.f * bc);
        float g64i = e64 * sinf(64.f * bc);
        float pr = state_re[m * CTX + c], pi = state_im[m * CTX + c];
        for (int q = 0; q < 128; q++) {
            Er[q] = pr; Ei[q] = pi;
            if (Rf[q]) { pr = Br[q]; pi = Bi[q]; }
            else {
                float nr = pr * g64r - pi * g64i + Br[q];
                pi       = pr * g64i + pi * g64r + Bi[q];
                pr = nr;
            }
        }
    }
    __syncthreads();
    sre = Er[j]; sim = Ei[j];
    unsigned int ore[32], oim[32];
    #pragma unroll
    for (int i = 0; i < 64; i++) {
        int t = t0 + i;
        if (rmask & (1ull << i)) { sre = 0.f; sim = 0.f; }
        else { float tr_ = sre * gr - sim * gi; sim = sre * gi + sim * gr; sre = tr_; }
        sre += gx[t];
        unsigned short hr = f2bf(sre), hi_ = f2bf(sim);
        if (i & 1) { ore[i >> 1] |= ((unsigned int)hr) << 16; oim[i >> 1] |= ((unsigned int)hi_) << 16; }
        else       { ore[i >> 1]  = hr;                        oim[i >> 1]  = hi_; }
    }
    if (j == 127) {     // exact fp32 final state (t = 8191)
        int p = m * CTX + c;
        fstate[p]        = sre;
        fstate[1024 + p] = sim;
    }

    unsigned short* zreb = zinTb + (size_t)(m * 32 + c)      * T_DIM;
    unsigned short* zimb = zinTb + (size_t)(m * 32 + 16 + c) * T_DIM;

    // --- re: stage to LDS, flush coalesced (2 KB per instruction across block) ---
    #pragma unroll
    for (int q = 0; q < 32; q++) SB[j * 33 + q] = ore[q];
    __syncthreads();
    #pragma unroll
    for (int it = 0; it < 8; it++) {
        int g = (it * 128 + j) * 4;           // uint index within 4096-uint row
        int jj = g >> 5, qq = g & 31;
        uint4 v = *(uint4*)&SB[jj * 33 + qq];
        *(uint4*)(zreb + g * 2) = v;
    }
    __syncthreads();
    // --- im ---
    #pragma unroll
    for (int q = 0; q < 32; q++) SB[j * 33 + q] = oim[q];
    __syncthreads();
    #pragma unroll
    for (int it = 0; it < 8; it++) {
        int g = (it * 128 + j) * 4;
        int jj = g >> 5, qq = g & 31;
        uint4 v = *(uint4*)&SB[jj * 33 + qq];
        *(uint4*)(zimb + g * 2) = v;
    }
}

// ---------------- T3: transpose zinTb[k][t] -> zinb[t][k], 64x64 tiles -------------------------
__global__ __launch_bounds__(256) void t3_tr(const unsigned short* __restrict__ zinTb,
                                             unsigned short* __restrict__ zinb)
{
    __shared__ unsigned short S[64][72];
    const int k0 = blockIdx.x * 64, t0 = blockIdx.y * 64;
    const int tid = threadIdx.x;
    {
        int kr = tid >> 3, tc = (tid & 7) * 8;
        #pragma unroll
        for (int p = 0; p < 2; p++) {
            int k = kr + p * 32;
            ushort4 a = *(const ushort4*)&zinTb[(size_t)(k0 + k) * T_DIM + t0 + tc];
            ushort4 b = *(const ushort4*)&zinTb[(size_t)(k0 + k) * T_DIM + t0 + tc + 4];
            *(ushort4*)&S[k][tc]     = a;
            *(ushort4*)&S[k][tc + 4] = b;
        }
    }
    __syncthreads();
    {
        int tr = tid >> 3, kc = (tid & 7) * 8;
        #pragma unroll
        for (int p = 0; p < 2; p++) {
            int t = tr + p * 32;
            ushort4 o1, o2;
            o1.x = S[kc+0][t]; o1.y = S[kc+1][t]; o1.z = S[kc+2][t]; o1.w = S[kc+3][t];
            o2.x = S[kc+4][t]; o2.y = S[kc+5][t]; o2.z = S[kc+6][t]; o2.w = S[kc+7][t];
            *(ushort4*)&zinb[(size_t)(t0 + t) * KMIX + k0 + kc]     = o1;
            *(ushort4*)&zinb[(size_t)(t0 + t) * KMIX + k0 + kc + 4] = o2;
        }
    }
}

// ---------------- GA: 32x32x16 MFMA. Fused [go+skip] phase then mix phase. XCD-swizzled -------
// A/B operand: row = lane&31, k = (lane>>5)*8 + j. C/D: col = lane&31,
// row = (reg&3) + 8*(reg>>2) + 4*(lane>>5)  [verified m74/m101].
__global__ __launch_bounds__(256, 2) void gA_gemm(
        const unsigned short* __restrict__ xb,   const unsigned short* __restrict__ zinb,
        const unsigned short* __restrict__ gob,  const unsigned short* __restrict__ skb,
        const unsigned short* __restrict__ mixb,
        const float* __restrict__ go_b, const float* __restrict__ skip_b, const float* __restrict__ mix_b,
        unsigned short* __restrict__ zg, unsigned short* __restrict__ sk2)
{
    __shared__ __align__(16) unsigned short As[4096];
    __shared__ __align__(16) unsigned short Bs[4096];
    __shared__ __align__(16) unsigned short Cs[4096];
    const int tid = threadIdx.x;
    const int b = blockIdx.x;
    const int xcd = b & 7, q = b >> 3;
    const int t0 = (xcd * 8 + (q >> 3)) * 128;
    const int n0 = (q & 7) * 128;

    const int lane = tid & 63, w = tid >> 6;
    const int wm = w >> 1, wn = w & 1;
    const int l31 = lane & 31, h = lane >> 5;
    const int r = tid >> 2, c8 = (tid & 3) * 8;

    unsigned short* lA0 = As + tid * 8;
    unsigned short* lA1 = As + 2048 + tid * 8;
    unsigned short* lB0 = Bs + tid * 8;
    unsigned short* lB1 = Bs + 2048 + tid * 8;
    unsigned short* lC0 = Cs + tid * 8;
    unsigned short* lC1 = Cs + 2048 + tid * 8;

    f32x16 accg[2][2], acck[2][2];
    #pragma unroll
    for (int mi = 0; mi < 2; mi++)
        #pragma unroll
        for (int ni = 0; ni < 2; ni++)
            #pragma unroll
            for (int e = 0; e < 16; e++) { accg[mi][ni][e] = 0.f; acck[mi][ni][e] = 0.f; }

    // ---- fused phase: go + skip (shared A = xb), K = 1024 ----
    {
        const unsigned short* gA0 = xb  + (size_t)(t0 + r)      * IN_DIM + c8;
        const unsigned short* gA1 = xb  + (size_t)(t0 + 64 + r) * IN_DIM + c8;
        const unsigned short* gB0 = gob + (size_t)(n0 + r)      * IN_DIM + c8;
        const unsigned short* gB1 = gob + (size_t)(n0 + 64 + r) * IN_DIM + c8;
        const unsigned short* gC0 = skb + (size_t)(n0 + r)      * IN_DIM + c8;
        const unsigned short* gC1 = skb + (size_t)(n0 + 64 + r) * IN_DIM + c8;
        for (int k0 = 0; k0 < IN_DIM; k0 += 32) {
            __syncthreads();
            gl2lds16(gA0 + k0, lA0);
            gl2lds16(gA1 + k0, lA1);
            gl2lds16(gB0 + k0, lB0);
            gl2lds16(gB1 + k0, lB1);
            gl2lds16(gC0 + k0, lC0);
            gl2lds16(gC1 + k0, lC1);
            asm volatile("s_waitcnt vmcnt(0)" ::: "memory");
            __syncthreads();
            #pragma unroll
            for (int kh = 0; kh < 2; kh++) {
                bf16x8 af[2], bg[2], bk[2];
                #pragma unroll
                for (int mi = 0; mi < 2; mi++)
                    af[mi] = *(const bf16x8*)&As[(wm * 64 + mi * 32 + l31) * 32 + kh * 16 + h * 8];
                #pragma unroll
                for (int ni = 0; ni < 2; ni++) {
                    bg[ni] = *(const bf16x8*)&Bs[(wn * 64 + ni * 32 + l31) * 32 + kh * 16 + h * 8];
                    bk[ni] = *(const bf16x8*)&Cs[(wn * 64 + ni * 32 + l31) * 32 + kh * 16 + h * 8];
                }
                #pragma unroll
                for (int mi = 0; mi < 2; mi++)
                    #pragma unroll
                    for (int ni = 0; ni < 2; ni++) {
                        accg[mi][ni] = __builtin_amdgcn_mfma_f32_32x32x16_bf16(af[mi], bg[ni], accg[mi][ni], 0, 0, 0);
                        acck[mi][ni] = __builtin_amdgcn_mfma_f32_32x32x16_bf16(af[mi], bk[ni], acck[mi][ni], 0, 0, 0);
                    }
            }
        }
    }

    // sigmoid (packed bf16 pairs) + sk2 write
    unsigned int sigp[32];
    #pragma unroll
    for (int mi = 0; mi < 2; mi++)
        #pragma unroll
        for (int ni = 0; ni < 2; ni++) {
            int n = n0 + wn * 64 + ni * 32 + l31;
            float gb = go_b[n];
            float sb_ = skip_b[n];
            #pragma unroll
            for (int reg = 0; reg < 16; reg++) {
                int row = (reg & 3) + 8 * (reg >> 2) + 4 * h;
                int t = t0 + wm * 64 + mi * 32 + row;
                float s = 1.f / (1.f + expf(-(accg[mi][ni][reg] + gb)));
                sk2[(size_t)t * OUT_DIM + n] = f2bf((acck[mi][ni][reg] + sb_) * (1.f - s));
                unsigned int pk = (unsigned int)f2bf(s);
                int idx = (mi * 2 + ni) * 8 + (reg >> 1);
                if (reg & 1) sigp[idx] |= pk << 16;
                else         sigp[idx]  = pk;
            }
        }

    // ---- mix phase, K = 2048 ----
    #pragma unroll
    for (int mi = 0; mi < 2; mi++)
        #pragma unroll
        for (int ni = 0; ni < 2; ni++)
            #pragma unroll
            for (int e = 0; e < 16; e++) accg[mi][ni][e] = 0.f;
    {
        const unsigned short* gA0 = zinb + (size_t)(t0 + r)      * KMIX + c8;
        const unsigned short* gA1 = zinb + (size_t)(t0 + 64 + r) * KMIX + c8;
        const unsigned short* gB0 = mixb + (size_t)(n0 + r)      * KMIX + c8;
        const unsigned short* gB1 = mixb + (size_t)(n0 + 64 + r) * KMIX + c8;
        for (int k0 = 0; k0 < KMIX; k0 += 32) {
            __syncthreads();
            gl2lds16(gA0 + k0, lA0);
            gl2lds16(gA1 + k0, lA1);
            gl2lds16(gB0 + k0, lB0);
            gl2lds16(gB1 + k0, lB1);
            asm volatile("s_waitcnt vmcnt(0)" ::: "memory");
            __syncthreads();
            #pragma unroll
            for (int kh = 0; kh < 2; kh++) {
                bf16x8 af[2], bf[2];
                #pragma unroll
                for (int mi = 0; mi < 2; mi++)
                    af[mi] = *(const bf16x8*)&As[(wm * 64 + mi * 32 + l31) * 32 + kh * 16 + h * 8];
                #pragma unroll
                for (int ni = 0; ni < 2; ni++)
                    bf[ni] = *(const bf16x8*)&Bs[(wn * 64 + ni * 32 + l31) * 32 + kh * 16 + h * 8];
                #pragma unroll
                for (int mi = 0; mi < 2; mi++)
                    #pragma unroll
                    for (int ni = 0; ni < 2; ni++)
                        accg[mi][ni] = __builtin_amdgcn_mfma_f32_32x32x16_bf16(af[mi], bf[ni], accg[mi][ni], 0, 0, 0);
            }
        }
    }

    #pragma unroll
    for (int mi = 0; mi < 2; mi++)
        #pragma unroll
        for (int ni = 0; ni < 2; ni++) {
            int n = n0 + wn * 64 + ni * 32 + l31;
            float mb_ = mix_b[n];
            #pragma unroll
            for (int reg = 0; reg < 16; reg++) {
                int row = (reg & 3) + 8 * (reg >> 2) + 4 * h;
                int t = t0 + wm * 64 + mi * 32 + row;
                unsigned int u = sigp[(mi * 2 + ni) * 8 + (reg >> 1)];
                float sig = bf2f((unsigned short)((reg & 1) ? (u >> 16) : (u & 0xffff)));
                zg[(size_t)t * OUT_DIM + n] = f2bf((accg[mi][ni][reg] + mb_) * sig);
            }
        }
}

// ---------------- G3: LayerNorm + residual (bf16 in, fp32 out) --------------------------------
__global__ __launch_bounds__(256) void g3_ln(const unsigned short* __restrict__ zg,
        const unsigned short* __restrict__ sk2, float* __restrict__ out)
{
    __shared__ float sb[4], qb[4];
    __shared__ float mu_s, rstd_s;
    const int t = blockIdx.x;
    const int tid = threadIdx.x;
    ushort4 zu = *(const ushort4*)&zg [(size_t)t * OUT_DIM + tid * 4];
    ushort4 su = *(const ushort4*)&sk2[(size_t)t * OUT_DIM + tid * 4];
    float z0 = bf2f(zu.x), z1 = bf2f(zu.y), z2 = bf2f(zu.z), z3 = bf2f(zu.w);
    float s0 = bf2f(su.x), s1 = bf2f(su.y), s2 = bf2f(su.z), s3 = bf2f(su.w);
    float s = z0 + z1 + z2 + z3;
    float q = z0*z0 + z1*z1 + z2*z2 + z3*z3;
    #pragma unroll
    for (int off = 32; off > 0; off >>= 1) {
        s += __shfl_down(s, off, 64);
        q += __shfl_down(q, off, 64);
    }
    int wid = tid >> 6;
    if ((tid & 63) == 0) { sb[wid] = s; qb[wid] = q; }
    __syncthreads();
    if (tid == 0) {
        float S = sb[0] + sb[1] + sb[2] + sb[3];
        float Q = qb[0] + qb[1] + qb[2] + qb[3];
        float mu = S * (1.f / 1024.f);
        float var = Q * (1.f / 1024.f) - mu * mu;
        mu_s = mu; rstd_s = rsqrtf(var + 1e-5f);
    }
    __syncthreads();
    float mu = mu_s, rs = rstd_s;
    float4 o;
    o.x = (z0 - mu) * rs + s0;
    o.y = (z1 - mu) * rs + s1;
    o.z = (z2 - mu) * rs + s2;
    o.w = (z3 - mu) * rs + s3;
    *(float4*)&out[(size_t)t * OUT_DIM + tid * 4] = o;
}

// ---------------- G4: final_state copy (planar re/im, guarded) --------------------------------
__global__ void g4_final(const float* __restrict__ fstate, float* __restrict__ out, int out_size)
{
    int i = blockIdx.x * blockDim.x + threadIdx.x;
    if (i >= 2048) return;
    long long base = (long long)T_DIM * OUT_DIM;
    if (base + i < (long long)out_size) out[base + i] = fstate[i];
}

extern "C" void kernel_launch(void* const* d_in, const int* in_sizes, int n_in,
                              void* d_out, int out_size, void* d_ws, size_t ws_size,
                              hipStream_t stream) {
    const float* x        = (const float*)d_in[0];
    const float* state_re = (const float*)d_in[1];
    const float* state_im = (const float*)d_in[2];
    const void*  startp   = d_in[3];
    const float* pre_w    = (const float*)d_in[5];
    const float* pre_b    = (const float*)d_in[6];
    const float* gi_w     = (const float*)d_in[7];
    const float* gi_b     = (const float*)d_in[8];
    const float* go_w     = (const float*)d_in[9];
    const float* go_b     = (const float*)d_in[10];
    const float* skip_w   = (const float*)d_in[11];
    const float* skip_b   = (const float*)d_in[12];
    const float* mix_w    = (const float*)d_in[13];
    const float* mix_b    = (const float*)d_in[14];
    const float* ffa_a    = (const float*)d_in[15];
    const float* ffa_b    = (const float*)d_in[16];

    float* ws = (float*)d_ws;
    float*          gxT    = ws;
    unsigned short* zinTb  = (unsigned short*)(ws + 524288);
    unsigned short* zinb   = (unsigned short*)(ws + 8912896);
    unsigned short* xb     = (unsigned short*)(ws + 17301504);
    unsigned short* gob    = (unsigned short*)(ws + 21495808);
    unsigned short* skb    = (unsigned short*)(ws + 22020096);
    unsigned short* mixb   = (unsigned short*)(ws + 22544384);
    unsigned short* zg     = (unsigned short*)(ws + 23592960);
    unsigned short* sk2    = (unsigned short*)(ws + 27787264);
    float*          fstate = ws + 31981568;
    unsigned char*  mask   = (unsigned char*)(ws + 31983616);
    unsigned short* pwb    = zg;            // borrow zg region pre-gA
    unsigned short* gwb    = zg + 65536;
    float* out = (float*)d_out;

    hipLaunchKernelGGL(k0_start, dim3(1),       dim3(1024), 0, stream, startp, mask);
    hipLaunchKernelGGL(c0_conv,  dim3(1536),    dim3(256),  0, stream, x, go_w, skip_w, mix_w, pre_w, gi_w,
                                                             xb, gob, skb, mixb, pwb, gwb);
    hipLaunchKernelGGL(k1_mfma,  dim3(256),     dim3(256),  0, stream, xb, pwb, gwb, pre_b, gi_b, gxT);
    hipLaunchKernelGGL(k2_scan,  dim3(1024),    dim3(128),  0, stream, gxT, mask, state_re, state_im, ffa_a, ffa_b, zinTb, fstate);
    hipLaunchKernelGGL(t3_tr,    dim3(32, 128), dim3(256),  0, stream, zinTb, zinb);
    hipLaunchKernelGGL(gA_gemm,  dim3(512),     dim3(256),  0, stream, xb, zinb, gob, skb, mixb, go_b, skip_b, mix_b, zg, sk2);
    hipLaunchKernelGGL(g3_ln,    dim3(8192),    dim3(256),  0, stream, zg, sk2, out);
    hipLaunchKernelGGL(g4_final, dim3(8),       dim3(256),  0, stream, fstate, out, out_size);
}